// Round 5
// baseline (12586.941 us; speedup 1.0000x reference)
//
#include <hip/hip_runtime.h>

// Decoder: B=256, T=128, ENC=256, DEC=256, OUT=3. All fp32 in/out.
//
// Round 5: round-4's overlap plan re-done spill-free. Round-4 lesson: f16x8
// ARRAYS (wb[8]/wpre[8]) went to scratch (WRITE_SIZE 384KB -> 6.3GB, rule#20);
// this version uses only individually NAMED f16x8 registers.
//  - depth-8 software pipeline (two named groups of 4) on a1/whh/wc streams.
//  - wc chunks 0..7 prefetched at Phase-Z start into wp0..wp7 (live Z->G),
//    completing under S/C where L2 would otherwise idle.
// Predicted: ~11.5-13 us/step -> 1.45-1.65 ms; VGPR ~100-128; WRITE_SIZE ~384KB.

#define TT 128
#define SCL 2.885390081777927f  // 2*log2(e)

typedef _Float16 h2v __attribute__((ext_vector_type(2)));
typedef _Float16 f16x4 __attribute__((ext_vector_type(4)));
typedef _Float16 f16x8 __attribute__((ext_vector_type(8)));

__device__ __forceinline__ float fdot2(h2v a, h2v b, float c) {
#if __has_builtin(__builtin_amdgcn_fdot2)
  return __builtin_amdgcn_fdot2(a, b, c, false);
#else
  return c + (float)a[0] * (float)b[0] + (float)a[1] * (float)b[1];
#endif
}

__device__ __forceinline__ float exp2_fast(float x) {
#if __has_builtin(__builtin_amdgcn_exp2f)
  return __builtin_amdgcn_exp2f(x);
#else
  return exp2f(x);
#endif
}
__device__ __forceinline__ float rcp_fast(float x) {
#if __has_builtin(__builtin_amdgcn_rcpf)
  return __builtin_amdgcn_rcpf(x);
#else
  return 1.f / x;
#endif
}

__device__ __forceinline__ float tanh_scaled(float s) {  // s = SCL*v
  return fmaf(-2.f, rcp_fast(exp2_fast(s) + 1.f), 1.f);
}
__device__ __forceinline__ float fast_sig(float x) {
  return rcp_fast(1.f + __expf(-x));
}
__device__ __forceinline__ float fast_tanh(float x) {
  return tanh_scaled(x * SCL);
}

__device__ __forceinline__ float dot8(f16x8 w, f16x8 h, float acc) {
  h2v w0 = __builtin_shufflevector(w, w, 0, 1), h0 = __builtin_shufflevector(h, h, 0, 1);
  h2v w1 = __builtin_shufflevector(w, w, 2, 3), h1 = __builtin_shufflevector(h, h, 2, 3);
  h2v w2 = __builtin_shufflevector(w, w, 4, 5), h2 = __builtin_shufflevector(h, h, 4, 5);
  h2v w3 = __builtin_shufflevector(w, w, 6, 7), h3 = __builtin_shufflevector(h, h, 6, 7);
  acc = fdot2(w0, h0, acc);
  acc = fdot2(w1, h1, acc);
  acc = fdot2(w2, h2, acc);
  acc = fdot2(w3, h3, acc);
  return acc;
}

// ---------------- precompute kernels ----------------

__global__ void k_transpose(const float* __restrict__ src, float* __restrict__ dst,
                            int R, int C) {
  int idx = blockIdx.x * 256 + threadIdx.x;
  if (idx >= R * C) return;
  int r = idx / C, c = idx - r * C;
  dst[(size_t)c * R + r] = src[idx];
}

// z2h[row][f] = SCL*(sum_e x[row][e]*attn2_w[f][e] + a2b[f] + a1b[f]) fp16
// + emits xTg[b][e][t] fp16 via 2x f16x8 vector stores per thread.
__global__ __launch_bounds__(256) void k_z2x(const float* __restrict__ x,
                                             const float* __restrict__ a2wT,
                                             const float* __restrict__ a2b,
                                             const float* __restrict__ a1b,
                                             _Float16* __restrict__ z2h,
                                             _Float16* __restrict__ xTg) {
  __shared__ float xt[16][257];
  const int r0 = blockIdx.x * 16;
  const int tid = threadIdx.x;
  for (int idx = tid; idx < 16 * 256; idx += 256) {
    int rr = idx >> 8, e = idx & 255;
    xt[rr][e] = x[(size_t)(r0 + rr) * 256 + e];
  }
  __syncthreads();
  const int f = tid;
  float bias = a2b[f] + a1b[f];
  float acc[16];
#pragma unroll
  for (int rr = 0; rr < 16; ++rr) acc[rr] = bias;
  for (int e = 0; e < 256; ++e) {
    float w = a2wT[(size_t)e * 256 + f];
#pragma unroll
    for (int rr = 0; rr < 16; ++rr) acc[rr] += w * xt[rr][e];
  }
#pragma unroll
  for (int rr = 0; rr < 16; ++rr)
    z2h[(size_t)(r0 + rr) * 256 + f] = (_Float16)(acc[rr] * SCL);
  const int bb = r0 >> 7, t0 = r0 & 127;
  f16x8 lo, hi;
#pragma unroll
  for (int rr = 0; rr < 8; ++rr) lo[rr] = (_Float16)xt[rr][f];
#pragma unroll
  for (int rr = 0; rr < 8; ++rr) hi[rr] = (_Float16)xt[8 + rr][f];
  _Float16* d = &xTg[((size_t)bb * 256 + f) * 128 + t0];
  *(f16x8*)d = lo;
  *(f16x8*)(d + 8) = hi;
}

// a1p8[kc][f][8] = attn1_w[f][kc*8+j] * SCL   (kc<64, f<256)
__global__ void k_pack_a1(const float* __restrict__ a1w, _Float16* __restrict__ dst) {
  int idx = blockIdx.x * 256 + threadIdx.x;  // 131072
  int j = idx & 7, f = (idx >> 3) & 255, kc = idx >> 11;
  dst[idx] = (_Float16)(a1w[(size_t)f * 512 + kc * 8 + j] * SCL);
}

// whh8[kc][n][8] = w_hh[n][kc*8+j]   (kc<32, n<1024)
__global__ void k_pack_whh(const float* __restrict__ whh, _Float16* __restrict__ dst) {
  int idx = blockIdx.x * 256 + threadIdx.x;  // 262144
  int j = idx & 7, n = (idx >> 3) & 1023, kc = idx >> 13;
  dst[idx] = (_Float16)whh[(size_t)n * 256 + kc * 8 + j];
}

// wc8[kc][n][8] fp16 of (w_ih @ tilde_w)[n][kc*8+j], k>=259 zero-pad (kc<33)
__global__ __launch_bounds__(320) void k_wcomb(const float* __restrict__ w_ih,
                                               const float* __restrict__ tilde_w,
                                               const float* __restrict__ tilde_b,
                                               const float* __restrict__ b_ih,
                                               const float* __restrict__ b_hh,
                                               _Float16* __restrict__ wc8,
                                               float* __restrict__ bcomb) {
  __shared__ float wrow[512];
  __shared__ float bred[320];
  const int n = blockIdx.x;
  const int tid = threadIdx.x;
  for (int j = tid; j < 512; j += 320) wrow[j] = w_ih[(size_t)n * 512 + j];
  __syncthreads();
  if (tid < 264) {
    float acc = 0.f;
    if (tid < 259)
      for (int j = 0; j < 512; ++j) acc += wrow[j] * tilde_w[(size_t)j * 259 + tid];
    wc8[(size_t)(tid >> 3) * 8192 + n * 8 + (tid & 7)] = (_Float16)acc;
  }
  float p = 0.f;
  for (int j = tid; j < 512; j += 320) p += wrow[j] * tilde_b[j];
  bred[tid] = p;
  __syncthreads();
  if (tid == 0) {
    float s = 0.f;
    for (int j = 0; j < 320; ++j) s += bred[j];
    bcomb[n] = s + b_ih[n] + b_hh[n];
  }
}

// whead[o][k] = fc2_w @ fc1_w; bhead[o] = fc2_w[o]·fc1_b + fc2_b[o]
__global__ __launch_bounds__(512) void k_whead(const float* __restrict__ fc1_w,
                                               const float* __restrict__ fc1_b,
                                               const float* __restrict__ fc2_w,
                                               const float* __restrict__ fc2_b,
                                               float* __restrict__ whead,
                                               float* __restrict__ bhead) {
  const int k = threadIdx.x;
#pragma unroll
  for (int o = 0; o < 3; ++o) {
    float acc = 0.f;
    for (int j = 0; j < 256; ++j) acc += fc2_w[o * 256 + j] * fc1_w[(size_t)j * 512 + k];
    whead[o * 512 + k] = acc;
  }
  if (k < 3) {
    float acc = fc2_b[k];
    for (int j = 0; j < 256; ++j) acc += fc2_w[k * 256 + j] * fc1_b[j];
    bhead[k] = acc;
  }
}

// ---------------- main persistent decoder ----------------

__global__ __launch_bounds__(1024, 4) void k_decoder(
    const _Float16* __restrict__ z2g,  // [32768][256] fp16, pre-scaled, incl biases
    const _Float16* __restrict__ xTg,  // [256][256 e][128 t] fp16
    const float* __restrict__ yg,      // y_seq [256][128][3] fp32
    const float* __restrict__ a3w,     // [256]
    const _Float16* __restrict__ a1p8, // [64 kc][256 f][8]
    const _Float16* __restrict__ whh8, // [32 kc][1024 n][8]
    const _Float16* __restrict__ wc8,  // [33 kc][1024 n][8]
    const float* __restrict__ bcomb,   // [1024]
    const float* __restrict__ whead,   // [3][512]
    const float* __restrict__ bhead,   // [3]
    float* __restrict__ outg)          // [256][128][3]
{
  __shared__ __align__(16) _Float16 z2s[128][260];
  __shared__ __align__(16) _Float16 xs[256][132];
  __shared__ float zpart[1024];
  __shared__ float scpart[1024];
  __shared__ float cpart[1024];
  __shared__ float gbuf[1024];
  __shared__ float z1c[256];
  __shared__ float hbuf[256], cbuf[256], ctxs[256], w3s[256];
  __shared__ __align__(16) _Float16 hc8[512];  // [h(256); c(256)]
  __shared__ __align__(16) _Float16 u8[264];   // [y(3); ctx(256); pad0(5)]
  __shared__ float attv[128];
  __shared__ float sred[8];

  const int b = blockIdx.x;
  const int tid = threadIdx.x;

  // stage z2[b] -> [t][260], xT[b] -> [e][132]
  {
    const f16x8* zsrc = (const f16x8*)(z2g + (size_t)b * TT * 256);
    for (int c = tid; c < 4096; c += 1024) {
      int t = c >> 5, fc = c & 31;
      f16x8 v = zsrc[c];
      f16x4 lo = __builtin_shufflevector(v, v, 0, 1, 2, 3);
      f16x4 hi = __builtin_shufflevector(v, v, 4, 5, 6, 7);
      _Float16* d = &z2s[t][fc * 8];
      *(f16x4*)d = lo;
      *(f16x4*)(d + 4) = hi;
    }
    const f16x8* xsrc = (const f16x8*)(xTg + (size_t)b * 256 * 128);
    for (int c = tid; c < 4096; c += 1024) {
      int e = c >> 4, tc = c & 15;
      f16x8 v = xsrc[c];
      f16x4 lo = __builtin_shufflevector(v, v, 0, 1, 2, 3);
      f16x4 hi = __builtin_shufflevector(v, v, 4, 5, 6, 7);
      _Float16* d = &xs[e][tc * 8];
      *(f16x4*)d = lo;
      *(f16x4*)(d + 4) = hi;
    }
  }
  if (tid < 256) {
    w3s[tid] = a3w[tid];
    hbuf[tid] = 0.f; cbuf[tid] = 0.f;
    hc8[tid] = (_Float16)0.f; hc8[256 + tid] = (_Float16)0.f;
  }
  if (tid >= 259 && tid < 264) u8[tid] = (_Float16)0.f;
  __syncthreads();  // B0

  const int f_z = tid & 255;
  const int qz = tid >> 8;  // k-quarter for z1 (wave-uniform)
  const f16x8* pa = (const f16x8*)a1p8 + ((size_t)(qz * 16) * 256 + f_z);
  const f16x8* pw = (const f16x8*)whh8 + tid;
  const f16x8* pc = (const f16x8*)wc8 + tid;
  const f16x8* hc8v = (const f16x8*)hc8;
  const f16x8* u8v = (const f16x8*)u8;
  const float bc = bcomb[tid];

#define HZ(i) hc8v[qz * 16 + (i)]
#define HH(i) hc8v[(i)]
#define UU(i) u8v[(i)]

  // head weights resident in registers
  float whr[8], bh = 0.f;
  if (tid < 192) {
    int o = tid >> 6, lane = tid & 63;
#pragma unroll
    for (int q2 = 0; q2 < 8; ++q2) whr[q2] = whead[o * 512 + lane + (q2 << 6)];
    bh = bhead[o];
  }

  for (int t = 0; t < TT; ++t) {
    float yreg = (tid < 3) ? yg[(size_t)(b * TT + t) * 3 + tid] : 0.f;

    // wc prefetch registers (named, live Phase Z -> Phase G)
    f16x8 wp0, wp1, wp2, wp3, wp4, wp5, wp6, wp7;

    // ---- Phase Z: z1 partials (4-way k-split) + gates_h (n = tid)
    float ghr;
    {
      // a1: 16 chunks, depth-8 pipeline (two named groups of 4)
      f16x8 a0 = pa[0 * 256], a1v = pa[1 * 256], a2 = pa[2 * 256], a3 = pa[3 * 256];
      f16x8 b0 = pa[4 * 256], b1 = pa[5 * 256], b2 = pa[6 * 256], b3 = pa[7 * 256];
      // issue wc prefetch now; completes under S/C
      wp0 = pc[(size_t)0 * 1024]; wp1 = pc[(size_t)1 * 1024];
      wp2 = pc[(size_t)2 * 1024]; wp3 = pc[(size_t)3 * 1024];
      wp4 = pc[(size_t)4 * 1024]; wp5 = pc[(size_t)5 * 1024];
      wp6 = pc[(size_t)6 * 1024]; wp7 = pc[(size_t)7 * 1024];
      float za0 = 0.f, za1 = 0.f, za2 = 0.f, za3 = 0.f;
      za0 = dot8(a0, HZ(0), za0); za1 = dot8(a1v, HZ(1), za1);
      za2 = dot8(a2, HZ(2), za2); za3 = dot8(a3, HZ(3), za3);
      a0 = pa[8 * 256]; a1v = pa[9 * 256]; a2 = pa[10 * 256]; a3 = pa[11 * 256];
      za0 = dot8(b0, HZ(4), za0); za1 = dot8(b1, HZ(5), za1);
      za2 = dot8(b2, HZ(6), za2); za3 = dot8(b3, HZ(7), za3);
      b0 = pa[12 * 256]; b1 = pa[13 * 256]; b2 = pa[14 * 256]; b3 = pa[15 * 256];
      za0 = dot8(a0, HZ(8), za0); za1 = dot8(a1v, HZ(9), za1);
      za2 = dot8(a2, HZ(10), za2); za3 = dot8(a3, HZ(11), za3);
      za0 = dot8(b0, HZ(12), za0); za1 = dot8(b1, HZ(13), za1);
      za2 = dot8(b2, HZ(14), za2); za3 = dot8(b3, HZ(15), za3);
      zpart[tid] = (za0 + za1) + (za2 + za3);

      // whh: 32 chunks, depth-8 pipeline
      f16x8 c0 = pw[(size_t)0 * 1024], c1 = pw[(size_t)1 * 1024],
            c2 = pw[(size_t)2 * 1024], c3 = pw[(size_t)3 * 1024];
      f16x8 d0 = pw[(size_t)4 * 1024], d1 = pw[(size_t)5 * 1024],
            d2 = pw[(size_t)6 * 1024], d3 = pw[(size_t)7 * 1024];
      float g0 = 0.f, g1 = 0.f, g2 = 0.f, g3 = 0.f;
      g0 = dot8(c0, HH(0), g0); g1 = dot8(c1, HH(1), g1);
      g2 = dot8(c2, HH(2), g2); g3 = dot8(c3, HH(3), g3);
      c0 = pw[(size_t)8 * 1024]; c1 = pw[(size_t)9 * 1024];
      c2 = pw[(size_t)10 * 1024]; c3 = pw[(size_t)11 * 1024];
      g0 = dot8(d0, HH(4), g0); g1 = dot8(d1, HH(5), g1);
      g2 = dot8(d2, HH(6), g2); g3 = dot8(d3, HH(7), g3);
      d0 = pw[(size_t)12 * 1024]; d1 = pw[(size_t)13 * 1024];
      d2 = pw[(size_t)14 * 1024]; d3 = pw[(size_t)15 * 1024];
      g0 = dot8(c0, HH(8), g0); g1 = dot8(c1, HH(9), g1);
      g2 = dot8(c2, HH(10), g2); g3 = dot8(c3, HH(11), g3);
      c0 = pw[(size_t)16 * 1024]; c1 = pw[(size_t)17 * 1024];
      c2 = pw[(size_t)18 * 1024]; c3 = pw[(size_t)19 * 1024];
      g0 = dot8(d0, HH(12), g0); g1 = dot8(d1, HH(13), g1);
      g2 = dot8(d2, HH(14), g2); g3 = dot8(d3, HH(15), g3);
      d0 = pw[(size_t)20 * 1024]; d1 = pw[(size_t)21 * 1024];
      d2 = pw[(size_t)22 * 1024]; d3 = pw[(size_t)23 * 1024];
      g0 = dot8(c0, HH(16), g0); g1 = dot8(c1, HH(17), g1);
      g2 = dot8(c2, HH(18), g2); g3 = dot8(c3, HH(19), g3);
      c0 = pw[(size_t)24 * 1024]; c1 = pw[(size_t)25 * 1024];
      c2 = pw[(size_t)26 * 1024]; c3 = pw[(size_t)27 * 1024];
      g0 = dot8(d0, HH(20), g0); g1 = dot8(d1, HH(21), g1);
      g2 = dot8(d2, HH(22), g2); g3 = dot8(d3, HH(23), g3);
      d0 = pw[(size_t)28 * 1024]; d1 = pw[(size_t)29 * 1024];
      d2 = pw[(size_t)30 * 1024]; d3 = pw[(size_t)31 * 1024];
      g0 = dot8(c0, HH(24), g0); g1 = dot8(c1, HH(25), g1);
      g2 = dot8(c2, HH(26), g2); g3 = dot8(c3, HH(27), g3);
      g0 = dot8(d0, HH(28), g0); g1 = dot8(d1, HH(29), g1);
      g2 = dot8(d2, HH(30), g2); g3 = dot8(d3, HH(31), g3);
      ghr = (g0 + g1) + (g2 + g3);
    }
    __syncthreads();  // B1

    if (tid < 256)
      z1c[tid] = zpart[tid] + zpart[tid + 256] + zpart[tid + 512] + zpart[tid + 768];
    __syncthreads();  // B2

    // ---- Phase S: scores; tp = tid&127, q = tid>>7 (8 groups x 32 f)
    {
      int tp = tid & 127, q = tid >> 7, f0 = q * 32;
      const _Float16* zr = &z2s[tp][f0];
      float acc = 0.f;
#pragma unroll
      for (int i = 0; i < 8; ++i) {
        f16x4 zz = *(const f16x4*)(zr + i * 4);
#pragma unroll
        for (int j = 0; j < 4; ++j) {
          int f = f0 + i * 4 + j;
          acc = fmaf(tanh_scaled(z1c[f] + (float)zz[j]), w3s[f], acc);
        }
      }
      scpart[tid] = acc;
    }
    __syncthreads();  // B3

    // ---- softmax (no max-sub: |score| <= sum|w3| ~ 25 << 88)
    if (tid < 128) {
      float sc = scpart[tid] + scpart[tid + 128] + scpart[tid + 256] + scpart[tid + 384] +
                 scpart[tid + 512] + scpart[tid + 640] + scpart[tid + 768] + scpart[tid + 896];
      float e = __expf(sc);
      attv[tid] = e;
      float s = e;
#pragma unroll
      for (int off = 32; off > 0; off >>= 1) s += __shfl_xor(s, off);
      if ((tid & 63) == 0) sred[2 + (tid >> 6)] = s;
    }
    __syncthreads();  // B4

    // ---- Phase C: context partials; e = tid&255, th4 = tid>>8 (4 x 32 t)
    {
      int e = tid & 255, th4 = tid >> 8;
      const _Float16* xr = &xs[e][th4 * 32];
      float acc = 0.f;
#pragma unroll
      for (int i = 0; i < 8; ++i) {
        f16x4 xv = *(const f16x4*)(xr + i * 4);
#pragma unroll
        for (int j = 0; j < 4; ++j)
          acc = fmaf(attv[th4 * 32 + i * 4 + j], (float)xv[j], acc);
      }
      cpart[tid] = acc;
    }
    __syncthreads();  // B5

    const float rsum = rcp_fast(sred[2] + sred[3]);
    if (tid < 256) {
      float cv = (cpart[tid] + cpart[tid + 256] + cpart[tid + 512] + cpart[tid + 768]) * rsum;
      ctxs[tid] = cv;
      u8[3 + tid] = (_Float16)cv;
    }
    if (tid < 3) u8[tid] = (_Float16)yreg;
    __syncthreads();  // B6

    // ---- Phase G: gates = W_comb·u + gates_h + b_comb (n = tid)
    {
      float a0 = 0.f, a1 = 0.f, a2 = 0.f, a3 = 0.f;
      // stream chunks 8..15 issue first (depth-8), then consume prefetch
      f16x8 c0 = pc[(size_t)8 * 1024], c1 = pc[(size_t)9 * 1024],
            c2 = pc[(size_t)10 * 1024], c3 = pc[(size_t)11 * 1024];
      f16x8 d0 = pc[(size_t)12 * 1024], d1 = pc[(size_t)13 * 1024],
            d2 = pc[(size_t)14 * 1024], d3 = pc[(size_t)15 * 1024];
      a0 = dot8(wp0, UU(0), a0); a1 = dot8(wp1, UU(1), a1);
      a2 = dot8(wp2, UU(2), a2); a3 = dot8(wp3, UU(3), a3);
      a0 = dot8(wp4, UU(4), a0); a1 = dot8(wp5, UU(5), a1);
      a2 = dot8(wp6, UU(6), a2); a3 = dot8(wp7, UU(7), a3);
      a0 = dot8(c0, UU(8), a0); a1 = dot8(c1, UU(9), a1);
      a2 = dot8(c2, UU(10), a2); a3 = dot8(c3, UU(11), a3);
      c0 = pc[(size_t)16 * 1024]; c1 = pc[(size_t)17 * 1024];
      c2 = pc[(size_t)18 * 1024]; c3 = pc[(size_t)19 * 1024];
      a0 = dot8(d0, UU(12), a0); a1 = dot8(d1, UU(13), a1);
      a2 = dot8(d2, UU(14), a2); a3 = dot8(d3, UU(15), a3);
      d0 = pc[(size_t)20 * 1024]; d1 = pc[(size_t)21 * 1024];
      d2 = pc[(size_t)22 * 1024]; d3 = pc[(size_t)23 * 1024];
      a0 = dot8(c0, UU(16), a0); a1 = dot8(c1, UU(17), a1);
      a2 = dot8(c2, UU(18), a2); a3 = dot8(c3, UU(19), a3);
      c0 = pc[(size_t)24 * 1024]; c1 = pc[(size_t)25 * 1024];
      c2 = pc[(size_t)26 * 1024]; c3 = pc[(size_t)27 * 1024];
      a0 = dot8(d0, UU(20), a0); a1 = dot8(d1, UU(21), a1);
      a2 = dot8(d2, UU(22), a2); a3 = dot8(d3, UU(23), a3);
      d0 = pc[(size_t)28 * 1024]; d1 = pc[(size_t)29 * 1024];
      d2 = pc[(size_t)30 * 1024]; d3 = pc[(size_t)31 * 1024];
      a0 = dot8(c0, UU(24), a0); a1 = dot8(c1, UU(25), a1);
      a2 = dot8(c2, UU(26), a2); a3 = dot8(c3, UU(27), a3);
      f16x8 tl = pc[(size_t)32 * 1024];
      a0 = dot8(d0, UU(28), a0); a1 = dot8(d1, UU(29), a1);
      a2 = dot8(d2, UU(30), a2); a3 = dot8(d3, UU(31), a3);
      a0 = dot8(tl, UU(32), a0);
      gbuf[tid] = (a0 + a1) + (a2 + a3) + ghr + bc;
    }
    __syncthreads();  // B7

    // ---- LSTM pointwise
    if (tid < 256) {
      float gi = gbuf[tid], gf = gbuf[tid + 256], gg = gbuf[tid + 512], go = gbuf[tid + 768];
      float cn = fast_sig(gf) * cbuf[tid] + fast_sig(gi) * fast_tanh(gg);
      float hn = fast_sig(go) * fast_tanh(cn);
      if (t < TT - 1) {  // reference skips state update on last step
        hbuf[tid] = hn; cbuf[tid] = cn;
        hc8[tid] = (_Float16)hn; hc8[256 + tid] = (_Float16)cn;
      }
    }
    __syncthreads();  // B8

    // ---- Phase H: out[b,t,o] = W_head[o]·[h2, ctx] + b_head[o]
    if (tid < 192) {
      int o = tid >> 6, lane = tid & 63;
      float acc = 0.f;
#pragma unroll
      for (int q2 = 0; q2 < 8; ++q2) {
        int k = lane + (q2 << 6);
        float v = (k < 256) ? hbuf[k] : ctxs[k - 256];
        acc = fmaf(whr[q2], v, acc);
      }
#pragma unroll
      for (int off = 32; off > 0; off >>= 1) acc += __shfl_xor(acc, off);
      if (lane == 0) outg[(size_t)(b * TT + t) * 3 + o] = acc + bh;
    }
    // no barrier: next phase writes only zpart (disjoint from hbuf/ctxs)
  }
#undef HZ
#undef HH
#undef UU
}

// ---------------- launch ----------------

extern "C" void kernel_launch(void* const* d_in, const int* in_sizes, int n_in,
                              void* d_out, int out_size, void* d_ws, size_t ws_size,
                              hipStream_t stream) {
  const float* x   = (const float*)d_in[0];
  const float* y   = (const float*)d_in[1];
  const float* a1w = (const float*)d_in[2];
  const float* a1b = (const float*)d_in[3];
  const float* a2w = (const float*)d_in[4];
  const float* a2b = (const float*)d_in[5];
  const float* a3w = (const float*)d_in[6];
  // d_in[7] = attn3_b: softmax-invariant constant, skipped
  const float* tw  = (const float*)d_in[8];
  const float* tb  = (const float*)d_in[9];
  const float* wih = (const float*)d_in[10];
  const float* whh = (const float*)d_in[11];
  const float* bih = (const float*)d_in[12];
  const float* bhh = (const float*)d_in[13];
  const float* f1w = (const float*)d_in[14];
  const float* f1b = (const float*)d_in[15];
  const float* f2w = (const float*)d_in[16];
  const float* f2b = (const float*)d_in[17];
  float* out = (float*)d_out;

  float* ws = (float*)d_ws;
  _Float16* z2h  = (_Float16*)ws;                       // 8,388,608 h = 4,194,304 f
  _Float16* xT   = (_Float16*)(ws + 4194304);           // 8,388,608 h
  float* a2wT    = ws + 8388608;                        // 65,536 f
  _Float16* a1p8 = (_Float16*)(ws + 8388608 + 65536);   // 131,072 h
  _Float16* whh8 = (_Float16*)(ws + 8388608 + 131072);  // 262,144 h
  _Float16* wc8  = (_Float16*)(ws + 8388608 + 262144);  // 270,336 h
  float* bcomb   = ws + 8388608 + 262144 + 135168;      // 1,024
  float* whead   = bcomb + 1024;                        // 1,536
  float* bhead   = whead + 1536;                        // 3

  k_transpose<<<dim3((256 * 256 + 255) / 256), dim3(256), 0, stream>>>(a2w, a2wT, 256, 256);
  k_z2x<<<dim3(2048), dim3(256), 0, stream>>>(x, a2wT, a2b, a1b, z2h, xT);
  k_pack_a1<<<dim3(512), dim3(256), 0, stream>>>(a1w, a1p8);
  k_pack_whh<<<dim3(1024), dim3(256), 0, stream>>>(whh, whh8);
  k_wcomb<<<dim3(1024), dim3(320), 0, stream>>>(wih, tw, tb, bih, bhh, wc8, bcomb);
  k_whead<<<dim3(1), dim3(512), 0, stream>>>(f1w, f1b, f2w, f2b, whead, bhead);

  k_decoder<<<dim3(256), dim3(1024), 0, stream>>>(z2h, xT, y, a3w, a1p8, whh8, wc8,
                                                  bcomb, whead, bhead, out);
}

// Round 6
// 12332.410 us; speedup vs baseline: 1.0206x; 1.0206x over previous
//
#include <hip/hip_runtime.h>

// Decoder: B=256, T=128, ENC=256, DEC=256, OUT=3. All fp32 in/out.
//
// Round 6: round-5 body, register file unlocked. Root cause of r4/r5 12.5ms:
// __launch_bounds__(1024,4) pinned the allocator to a 64-VGPR budget
// (8 waves/EU cap; VGPR_Count=64 across r3/4/5), so the prefetch/pipeline
// state spilled to scratch (WRITE_SIZE 384KB -> 6.29GB, byte-identical r4/r5).
// Fix: __launch_bounds__(1024) + amdgpu_waves_per_eu(4,4) -> 128-VGPR budget
// (LDS 158KB already limits to one 16-wave WG/CU, so no occupancy loss).
// Predicted: VGPR ~104-128, WRITE_SIZE ~384KB, ~11.5-13 us/step -> 1.45-1.7ms.

#define TT 128
#define SCL 2.885390081777927f  // 2*log2(e)

typedef _Float16 h2v __attribute__((ext_vector_type(2)));
typedef _Float16 f16x4 __attribute__((ext_vector_type(4)));
typedef _Float16 f16x8 __attribute__((ext_vector_type(8)));

__device__ __forceinline__ float fdot2(h2v a, h2v b, float c) {
#if __has_builtin(__builtin_amdgcn_fdot2)
  return __builtin_amdgcn_fdot2(a, b, c, false);
#else
  return c + (float)a[0] * (float)b[0] + (float)a[1] * (float)b[1];
#endif
}

__device__ __forceinline__ float exp2_fast(float x) {
#if __has_builtin(__builtin_amdgcn_exp2f)
  return __builtin_amdgcn_exp2f(x);
#else
  return exp2f(x);
#endif
}
__device__ __forceinline__ float rcp_fast(float x) {
#if __has_builtin(__builtin_amdgcn_rcpf)
  return __builtin_amdgcn_rcpf(x);
#else
  return 1.f / x;
#endif
}

__device__ __forceinline__ float tanh_scaled(float s) {  // s = SCL*v
  return fmaf(-2.f, rcp_fast(exp2_fast(s) + 1.f), 1.f);
}
__device__ __forceinline__ float fast_sig(float x) {
  return rcp_fast(1.f + __expf(-x));
}
__device__ __forceinline__ float fast_tanh(float x) {
  return tanh_scaled(x * SCL);
}

__device__ __forceinline__ float dot8(f16x8 w, f16x8 h, float acc) {
  h2v w0 = __builtin_shufflevector(w, w, 0, 1), h0 = __builtin_shufflevector(h, h, 0, 1);
  h2v w1 = __builtin_shufflevector(w, w, 2, 3), h1 = __builtin_shufflevector(h, h, 2, 3);
  h2v w2 = __builtin_shufflevector(w, w, 4, 5), h2 = __builtin_shufflevector(h, h, 4, 5);
  h2v w3 = __builtin_shufflevector(w, w, 6, 7), h3 = __builtin_shufflevector(h, h, 6, 7);
  acc = fdot2(w0, h0, acc);
  acc = fdot2(w1, h1, acc);
  acc = fdot2(w2, h2, acc);
  acc = fdot2(w3, h3, acc);
  return acc;
}

// ---------------- precompute kernels ----------------

__global__ void k_transpose(const float* __restrict__ src, float* __restrict__ dst,
                            int R, int C) {
  int idx = blockIdx.x * 256 + threadIdx.x;
  if (idx >= R * C) return;
  int r = idx / C, c = idx - r * C;
  dst[(size_t)c * R + r] = src[idx];
}

// z2h[row][f] = SCL*(sum_e x[row][e]*attn2_w[f][e] + a2b[f] + a1b[f]) fp16
// + emits xTg[b][e][t] fp16 via 2x f16x8 vector stores per thread.
__global__ __launch_bounds__(256) void k_z2x(const float* __restrict__ x,
                                             const float* __restrict__ a2wT,
                                             const float* __restrict__ a2b,
                                             const float* __restrict__ a1b,
                                             _Float16* __restrict__ z2h,
                                             _Float16* __restrict__ xTg) {
  __shared__ float xt[16][257];
  const int r0 = blockIdx.x * 16;
  const int tid = threadIdx.x;
  for (int idx = tid; idx < 16 * 256; idx += 256) {
    int rr = idx >> 8, e = idx & 255;
    xt[rr][e] = x[(size_t)(r0 + rr) * 256 + e];
  }
  __syncthreads();
  const int f = tid;
  float bias = a2b[f] + a1b[f];
  float acc[16];
#pragma unroll
  for (int rr = 0; rr < 16; ++rr) acc[rr] = bias;
  for (int e = 0; e < 256; ++e) {
    float w = a2wT[(size_t)e * 256 + f];
#pragma unroll
    for (int rr = 0; rr < 16; ++rr) acc[rr] += w * xt[rr][e];
  }
#pragma unroll
  for (int rr = 0; rr < 16; ++rr)
    z2h[(size_t)(r0 + rr) * 256 + f] = (_Float16)(acc[rr] * SCL);
  const int bb = r0 >> 7, t0 = r0 & 127;
  f16x8 lo, hi;
#pragma unroll
  for (int rr = 0; rr < 8; ++rr) lo[rr] = (_Float16)xt[rr][f];
#pragma unroll
  for (int rr = 0; rr < 8; ++rr) hi[rr] = (_Float16)xt[8 + rr][f];
  _Float16* d = &xTg[((size_t)bb * 256 + f) * 128 + t0];
  *(f16x8*)d = lo;
  *(f16x8*)(d + 8) = hi;
}

// a1p8[kc][f][8] = attn1_w[f][kc*8+j] * SCL   (kc<64, f<256)
__global__ void k_pack_a1(const float* __restrict__ a1w, _Float16* __restrict__ dst) {
  int idx = blockIdx.x * 256 + threadIdx.x;  // 131072
  int j = idx & 7, f = (idx >> 3) & 255, kc = idx >> 11;
  dst[idx] = (_Float16)(a1w[(size_t)f * 512 + kc * 8 + j] * SCL);
}

// whh8[kc][n][8] = w_hh[n][kc*8+j]   (kc<32, n<1024)
__global__ void k_pack_whh(const float* __restrict__ whh, _Float16* __restrict__ dst) {
  int idx = blockIdx.x * 256 + threadIdx.x;  // 262144
  int j = idx & 7, n = (idx >> 3) & 1023, kc = idx >> 13;
  dst[idx] = (_Float16)whh[(size_t)n * 256 + kc * 8 + j];
}

// wc8[kc][n][8] fp16 of (w_ih @ tilde_w)[n][kc*8+j], k>=259 zero-pad (kc<33)
__global__ __launch_bounds__(320) void k_wcomb(const float* __restrict__ w_ih,
                                               const float* __restrict__ tilde_w,
                                               const float* __restrict__ tilde_b,
                                               const float* __restrict__ b_ih,
                                               const float* __restrict__ b_hh,
                                               _Float16* __restrict__ wc8,
                                               float* __restrict__ bcomb) {
  __shared__ float wrow[512];
  __shared__ float bred[320];
  const int n = blockIdx.x;
  const int tid = threadIdx.x;
  for (int j = tid; j < 512; j += 320) wrow[j] = w_ih[(size_t)n * 512 + j];
  __syncthreads();
  if (tid < 264) {
    float acc = 0.f;
    if (tid < 259)
      for (int j = 0; j < 512; ++j) acc += wrow[j] * tilde_w[(size_t)j * 259 + tid];
    wc8[(size_t)(tid >> 3) * 8192 + n * 8 + (tid & 7)] = (_Float16)acc;
  }
  float p = 0.f;
  for (int j = tid; j < 512; j += 320) p += wrow[j] * tilde_b[j];
  bred[tid] = p;
  __syncthreads();
  if (tid == 0) {
    float s = 0.f;
    for (int j = 0; j < 320; ++j) s += bred[j];
    bcomb[n] = s + b_ih[n] + b_hh[n];
  }
}

// whead[o][k] = fc2_w @ fc1_w; bhead[o] = fc2_w[o]·fc1_b + fc2_b[o]
__global__ __launch_bounds__(512) void k_whead(const float* __restrict__ fc1_w,
                                               const float* __restrict__ fc1_b,
                                               const float* __restrict__ fc2_w,
                                               const float* __restrict__ fc2_b,
                                               float* __restrict__ whead,
                                               float* __restrict__ bhead) {
  const int k = threadIdx.x;
#pragma unroll
  for (int o = 0; o < 3; ++o) {
    float acc = 0.f;
    for (int j = 0; j < 256; ++j) acc += fc2_w[o * 256 + j] * fc1_w[(size_t)j * 512 + k];
    whead[o * 512 + k] = acc;
  }
  if (k < 3) {
    float acc = fc2_b[k];
    for (int j = 0; j < 256; ++j) acc += fc2_w[k * 256 + j] * fc1_b[j];
    bhead[k] = acc;
  }
}

// ---------------- main persistent decoder ----------------

__global__ __launch_bounds__(1024)
__attribute__((amdgpu_waves_per_eu(4, 4))) void k_decoder(
    const _Float16* __restrict__ z2g,  // [32768][256] fp16, pre-scaled, incl biases
    const _Float16* __restrict__ xTg,  // [256][256 e][128 t] fp16
    const float* __restrict__ yg,      // y_seq [256][128][3] fp32
    const float* __restrict__ a3w,     // [256]
    const _Float16* __restrict__ a1p8, // [64 kc][256 f][8]
    const _Float16* __restrict__ whh8, // [32 kc][1024 n][8]
    const _Float16* __restrict__ wc8,  // [33 kc][1024 n][8]
    const float* __restrict__ bcomb,   // [1024]
    const float* __restrict__ whead,   // [3][512]
    const float* __restrict__ bhead,   // [3]
    float* __restrict__ outg)          // [256][128][3]
{
  __shared__ __align__(16) _Float16 z2s[128][260];
  __shared__ __align__(16) _Float16 xs[256][132];
  __shared__ float zpart[1024];
  __shared__ float scpart[1024];
  __shared__ float cpart[1024];
  __shared__ float gbuf[1024];
  __shared__ float z1c[256];
  __shared__ float hbuf[256], cbuf[256], ctxs[256], w3s[256];
  __shared__ __align__(16) _Float16 hc8[512];  // [h(256); c(256)]
  __shared__ __align__(16) _Float16 u8[264];   // [y(3); ctx(256); pad0(5)]
  __shared__ float attv[128];
  __shared__ float sred[8];

  const int b = blockIdx.x;
  const int tid = threadIdx.x;

  // stage z2[b] -> [t][260], xT[b] -> [e][132]
  {
    const f16x8* zsrc = (const f16x8*)(z2g + (size_t)b * TT * 256);
    for (int c = tid; c < 4096; c += 1024) {
      int t = c >> 5, fc = c & 31;
      f16x8 v = zsrc[c];
      f16x4 lo = __builtin_shufflevector(v, v, 0, 1, 2, 3);
      f16x4 hi = __builtin_shufflevector(v, v, 4, 5, 6, 7);
      _Float16* d = &z2s[t][fc * 8];
      *(f16x4*)d = lo;
      *(f16x4*)(d + 4) = hi;
    }
    const f16x8* xsrc = (const f16x8*)(xTg + (size_t)b * 256 * 128);
    for (int c = tid; c < 4096; c += 1024) {
      int e = c >> 4, tc = c & 15;
      f16x8 v = xsrc[c];
      f16x4 lo = __builtin_shufflevector(v, v, 0, 1, 2, 3);
      f16x4 hi = __builtin_shufflevector(v, v, 4, 5, 6, 7);
      _Float16* d = &xs[e][tc * 8];
      *(f16x4*)d = lo;
      *(f16x4*)(d + 4) = hi;
    }
  }
  if (tid < 256) {
    w3s[tid] = a3w[tid];
    hbuf[tid] = 0.f; cbuf[tid] = 0.f;
    hc8[tid] = (_Float16)0.f; hc8[256 + tid] = (_Float16)0.f;
  }
  if (tid >= 259 && tid < 264) u8[tid] = (_Float16)0.f;
  __syncthreads();  // B0

  const int f_z = tid & 255;
  const int qz = tid >> 8;  // k-quarter for z1 (wave-uniform)
  const f16x8* pa = (const f16x8*)a1p8 + ((size_t)(qz * 16) * 256 + f_z);
  const f16x8* pw = (const f16x8*)whh8 + tid;
  const f16x8* pc = (const f16x8*)wc8 + tid;
  const f16x8* hc8v = (const f16x8*)hc8;
  const f16x8* u8v = (const f16x8*)u8;
  const float bc = bcomb[tid];

#define HZ(i) hc8v[qz * 16 + (i)]
#define HH(i) hc8v[(i)]
#define UU(i) u8v[(i)]

  // head weights resident in registers
  float whr[8], bh = 0.f;
  if (tid < 192) {
    int o = tid >> 6, lane = tid & 63;
#pragma unroll
    for (int q2 = 0; q2 < 8; ++q2) whr[q2] = whead[o * 512 + lane + (q2 << 6)];
    bh = bhead[o];
  }

  for (int t = 0; t < TT; ++t) {
    float yreg = (tid < 3) ? yg[(size_t)(b * TT + t) * 3 + tid] : 0.f;

    // wc prefetch registers (named, live Phase Z -> Phase G)
    f16x8 wp0, wp1, wp2, wp3, wp4, wp5, wp6, wp7;

    // ---- Phase Z: z1 partials (4-way k-split) + gates_h (n = tid)
    float ghr;
    {
      // a1: 16 chunks, depth-8 pipeline (two named groups of 4)
      f16x8 a0 = pa[0 * 256], a1v = pa[1 * 256], a2 = pa[2 * 256], a3 = pa[3 * 256];
      f16x8 b0 = pa[4 * 256], b1 = pa[5 * 256], b2 = pa[6 * 256], b3 = pa[7 * 256];
      // issue wc prefetch now; completes under S/C
      wp0 = pc[(size_t)0 * 1024]; wp1 = pc[(size_t)1 * 1024];
      wp2 = pc[(size_t)2 * 1024]; wp3 = pc[(size_t)3 * 1024];
      wp4 = pc[(size_t)4 * 1024]; wp5 = pc[(size_t)5 * 1024];
      wp6 = pc[(size_t)6 * 1024]; wp7 = pc[(size_t)7 * 1024];
      float za0 = 0.f, za1 = 0.f, za2 = 0.f, za3 = 0.f;
      za0 = dot8(a0, HZ(0), za0); za1 = dot8(a1v, HZ(1), za1);
      za2 = dot8(a2, HZ(2), za2); za3 = dot8(a3, HZ(3), za3);
      a0 = pa[8 * 256]; a1v = pa[9 * 256]; a2 = pa[10 * 256]; a3 = pa[11 * 256];
      za0 = dot8(b0, HZ(4), za0); za1 = dot8(b1, HZ(5), za1);
      za2 = dot8(b2, HZ(6), za2); za3 = dot8(b3, HZ(7), za3);
      b0 = pa[12 * 256]; b1 = pa[13 * 256]; b2 = pa[14 * 256]; b3 = pa[15 * 256];
      za0 = dot8(a0, HZ(8), za0); za1 = dot8(a1v, HZ(9), za1);
      za2 = dot8(a2, HZ(10), za2); za3 = dot8(a3, HZ(11), za3);
      za0 = dot8(b0, HZ(12), za0); za1 = dot8(b1, HZ(13), za1);
      za2 = dot8(b2, HZ(14), za2); za3 = dot8(b3, HZ(15), za3);
      zpart[tid] = (za0 + za1) + (za2 + za3);

      // whh: 32 chunks, depth-8 pipeline
      f16x8 c0 = pw[(size_t)0 * 1024], c1 = pw[(size_t)1 * 1024],
            c2 = pw[(size_t)2 * 1024], c3 = pw[(size_t)3 * 1024];
      f16x8 d0 = pw[(size_t)4 * 1024], d1 = pw[(size_t)5 * 1024],
            d2 = pw[(size_t)6 * 1024], d3 = pw[(size_t)7 * 1024];
      float g0 = 0.f, g1 = 0.f, g2 = 0.f, g3 = 0.f;
      g0 = dot8(c0, HH(0), g0); g1 = dot8(c1, HH(1), g1);
      g2 = dot8(c2, HH(2), g2); g3 = dot8(c3, HH(3), g3);
      c0 = pw[(size_t)8 * 1024]; c1 = pw[(size_t)9 * 1024];
      c2 = pw[(size_t)10 * 1024]; c3 = pw[(size_t)11 * 1024];
      g0 = dot8(d0, HH(4), g0); g1 = dot8(d1, HH(5), g1);
      g2 = dot8(d2, HH(6), g2); g3 = dot8(d3, HH(7), g3);
      d0 = pw[(size_t)12 * 1024]; d1 = pw[(size_t)13 * 1024];
      d2 = pw[(size_t)14 * 1024]; d3 = pw[(size_t)15 * 1024];
      g0 = dot8(c0, HH(8), g0); g1 = dot8(c1, HH(9), g1);
      g2 = dot8(c2, HH(10), g2); g3 = dot8(c3, HH(11), g3);
      c0 = pw[(size_t)16 * 1024]; c1 = pw[(size_t)17 * 1024];
      c2 = pw[(size_t)18 * 1024]; c3 = pw[(size_t)19 * 1024];
      g0 = dot8(d0, HH(12), g0); g1 = dot8(d1, HH(13), g1);
      g2 = dot8(d2, HH(14), g2); g3 = dot8(d3, HH(15), g3);
      d0 = pw[(size_t)20 * 1024]; d1 = pw[(size_t)21 * 1024];
      d2 = pw[(size_t)22 * 1024]; d3 = pw[(size_t)23 * 1024];
      g0 = dot8(c0, HH(16), g0); g1 = dot8(c1, HH(17), g1);
      g2 = dot8(c2, HH(18), g2); g3 = dot8(c3, HH(19), g3);
      c0 = pw[(size_t)24 * 1024]; c1 = pw[(size_t)25 * 1024];
      c2 = pw[(size_t)26 * 1024]; c3 = pw[(size_t)27 * 1024];
      g0 = dot8(d0, HH(20), g0); g1 = dot8(d1, HH(21), g1);
      g2 = dot8(d2, HH(22), g2); g3 = dot8(d3, HH(23), g3);
      d0 = pw[(size_t)28 * 1024]; d1 = pw[(size_t)29 * 1024];
      d2 = pw[(size_t)30 * 1024]; d3 = pw[(size_t)31 * 1024];
      g0 = dot8(c0, HH(24), g0); g1 = dot8(c1, HH(25), g1);
      g2 = dot8(c2, HH(26), g2); g3 = dot8(c3, HH(27), g3);
      g0 = dot8(d0, HH(28), g0); g1 = dot8(d1, HH(29), g1);
      g2 = dot8(d2, HH(30), g2); g3 = dot8(d3, HH(31), g3);
      ghr = (g0 + g1) + (g2 + g3);
    }
    __syncthreads();  // B1

    if (tid < 256)
      z1c[tid] = zpart[tid] + zpart[tid + 256] + zpart[tid + 512] + zpart[tid + 768];
    __syncthreads();  // B2

    // ---- Phase S: scores; tp = tid&127, q = tid>>7 (8 groups x 32 f)
    {
      int tp = tid & 127, q = tid >> 7, f0 = q * 32;
      const _Float16* zr = &z2s[tp][f0];
      float acc = 0.f;
#pragma unroll
      for (int i = 0; i < 8; ++i) {
        f16x4 zz = *(const f16x4*)(zr + i * 4);
#pragma unroll
        for (int j = 0; j < 4; ++j) {
          int f = f0 + i * 4 + j;
          acc = fmaf(tanh_scaled(z1c[f] + (float)zz[j]), w3s[f], acc);
        }
      }
      scpart[tid] = acc;
    }
    __syncthreads();  // B3

    // ---- softmax (no max-sub: |score| <= sum|w3| ~ 25 << 88)
    if (tid < 128) {
      float sc = scpart[tid] + scpart[tid + 128] + scpart[tid + 256] + scpart[tid + 384] +
                 scpart[tid + 512] + scpart[tid + 640] + scpart[tid + 768] + scpart[tid + 896];
      float e = __expf(sc);
      attv[tid] = e;
      float s = e;
#pragma unroll
      for (int off = 32; off > 0; off >>= 1) s += __shfl_xor(s, off);
      if ((tid & 63) == 0) sred[2 + (tid >> 6)] = s;
    }
    __syncthreads();  // B4

    // ---- Phase C: context partials; e = tid&255, th4 = tid>>8 (4 x 32 t)
    {
      int e = tid & 255, th4 = tid >> 8;
      const _Float16* xr = &xs[e][th4 * 32];
      float acc = 0.f;
#pragma unroll
      for (int i = 0; i < 8; ++i) {
        f16x4 xv = *(const f16x4*)(xr + i * 4);
#pragma unroll
        for (int j = 0; j < 4; ++j)
          acc = fmaf(attv[th4 * 32 + i * 4 + j], (float)xv[j], acc);
      }
      cpart[tid] = acc;
    }
    __syncthreads();  // B5

    const float rsum = rcp_fast(sred[2] + sred[3]);
    if (tid < 256) {
      float cv = (cpart[tid] + cpart[tid + 256] + cpart[tid + 512] + cpart[tid + 768]) * rsum;
      ctxs[tid] = cv;
      u8[3 + tid] = (_Float16)cv;
    }
    if (tid < 3) u8[tid] = (_Float16)yreg;
    __syncthreads();  // B6

    // ---- Phase G: gates = W_comb·u + gates_h + b_comb (n = tid)
    {
      float a0 = 0.f, a1 = 0.f, a2 = 0.f, a3 = 0.f;
      // stream chunks 8..15 issue first (depth-8), then consume prefetch
      f16x8 c0 = pc[(size_t)8 * 1024], c1 = pc[(size_t)9 * 1024],
            c2 = pc[(size_t)10 * 1024], c3 = pc[(size_t)11 * 1024];
      f16x8 d0 = pc[(size_t)12 * 1024], d1 = pc[(size_t)13 * 1024],
            d2 = pc[(size_t)14 * 1024], d3 = pc[(size_t)15 * 1024];
      a0 = dot8(wp0, UU(0), a0); a1 = dot8(wp1, UU(1), a1);
      a2 = dot8(wp2, UU(2), a2); a3 = dot8(wp3, UU(3), a3);
      a0 = dot8(wp4, UU(4), a0); a1 = dot8(wp5, UU(5), a1);
      a2 = dot8(wp6, UU(6), a2); a3 = dot8(wp7, UU(7), a3);
      a0 = dot8(c0, UU(8), a0); a1 = dot8(c1, UU(9), a1);
      a2 = dot8(c2, UU(10), a2); a3 = dot8(c3, UU(11), a3);
      c0 = pc[(size_t)16 * 1024]; c1 = pc[(size_t)17 * 1024];
      c2 = pc[(size_t)18 * 1024]; c3 = pc[(size_t)19 * 1024];
      a0 = dot8(d0, UU(12), a0); a1 = dot8(d1, UU(13), a1);
      a2 = dot8(d2, UU(14), a2); a3 = dot8(d3, UU(15), a3);
      d0 = pc[(size_t)20 * 1024]; d1 = pc[(size_t)21 * 1024];
      d2 = pc[(size_t)22 * 1024]; d3 = pc[(size_t)23 * 1024];
      a0 = dot8(c0, UU(16), a0); a1 = dot8(c1, UU(17), a1);
      a2 = dot8(c2, UU(18), a2); a3 = dot8(c3, UU(19), a3);
      c0 = pc[(size_t)24 * 1024]; c1 = pc[(size_t)25 * 1024];
      c2 = pc[(size_t)26 * 1024]; c3 = pc[(size_t)27 * 1024];
      a0 = dot8(d0, UU(20), a0); a1 = dot8(d1, UU(21), a1);
      a2 = dot8(d2, UU(22), a2); a3 = dot8(d3, UU(23), a3);
      d0 = pc[(size_t)28 * 1024]; d1 = pc[(size_t)29 * 1024];
      d2 = pc[(size_t)30 * 1024]; d3 = pc[(size_t)31 * 1024];
      a0 = dot8(c0, UU(24), a0); a1 = dot8(c1, UU(25), a1);
      a2 = dot8(c2, UU(26), a2); a3 = dot8(c3, UU(27), a3);
      f16x8 tl = pc[(size_t)32 * 1024];
      a0 = dot8(d0, UU(28), a0); a1 = dot8(d1, UU(29), a1);
      a2 = dot8(d2, UU(30), a2); a3 = dot8(d3, UU(31), a3);
      a0 = dot8(tl, UU(32), a0);
      gbuf[tid] = (a0 + a1) + (a2 + a3) + ghr + bc;
    }
    __syncthreads();  // B7

    // ---- LSTM pointwise
    if (tid < 256) {
      float gi = gbuf[tid], gf = gbuf[tid + 256], gg = gbuf[tid + 512], go = gbuf[tid + 768];
      float cn = fast_sig(gf) * cbuf[tid] + fast_sig(gi) * fast_tanh(gg);
      float hn = fast_sig(go) * fast_tanh(cn);
      if (t < TT - 1) {  // reference skips state update on last step
        hbuf[tid] = hn; cbuf[tid] = cn;
        hc8[tid] = (_Float16)hn; hc8[256 + tid] = (_Float16)cn;
      }
    }
    __syncthreads();  // B8

    // ---- Phase H: out[b,t,o] = W_head[o]·[h2, ctx] + b_head[o]
    if (tid < 192) {
      int o = tid >> 6, lane = tid & 63;
      float acc = 0.f;
#pragma unroll
      for (int q2 = 0; q2 < 8; ++q2) {
        int k = lane + (q2 << 6);
        float v = (k < 256) ? hbuf[k] : ctxs[k - 256];
        acc = fmaf(whr[q2], v, acc);
      }
#pragma unroll
      for (int off = 32; off > 0; off >>= 1) acc += __shfl_xor(acc, off);
      if (lane == 0) outg[(size_t)(b * TT + t) * 3 + o] = acc + bh;
    }
    // no barrier: next phase writes only zpart (disjoint from hbuf/ctxs)
  }
#undef HZ
#undef HH
#undef UU
}

// ---------------- launch ----------------

extern "C" void kernel_launch(void* const* d_in, const int* in_sizes, int n_in,
                              void* d_out, int out_size, void* d_ws, size_t ws_size,
                              hipStream_t stream) {
  const float* x   = (const float*)d_in[0];
  const float* y   = (const float*)d_in[1];
  const float* a1w = (const float*)d_in[2];
  const float* a1b = (const float*)d_in[3];
  const float* a2w = (const float*)d_in[4];
  const float* a2b = (const float*)d_in[5];
  const float* a3w = (const float*)d_in[6];
  // d_in[7] = attn3_b: softmax-invariant constant, skipped
  const float* tw  = (const float*)d_in[8];
  const float* tb  = (const float*)d_in[9];
  const float* wih = (const float*)d_in[10];
  const float* whh = (const float*)d_in[11];
  const float* bih = (const float*)d_in[12];
  const float* bhh = (const float*)d_in[13];
  const float* f1w = (const float*)d_in[14];
  const float* f1b = (const float*)d_in[15];
  const float* f2w = (const float*)d_in[16];
  const float* f2b = (const float*)d_in[17];
  float* out = (float*)d_out;

  float* ws = (float*)d_ws;
  _Float16* z2h  = (_Float16*)ws;                       // 8,388,608 h = 4,194,304 f
  _Float16* xT   = (_Float16*)(ws + 4194304);           // 8,388,608 h
  float* a2wT    = ws + 8388608;                        // 65,536 f
  _Float16* a1p8 = (_Float16*)(ws + 8388608 + 65536);   // 131,072 h
  _Float16* whh8 = (_Float16*)(ws + 8388608 + 131072);  // 262,144 h
  _Float16* wc8  = (_Float16*)(ws + 8388608 + 262144);  // 270,336 h
  float* bcomb   = ws + 8388608 + 262144 + 135168;      // 1,024
  float* whead   = bcomb + 1024;                        // 1,536
  float* bhead   = whead + 1536;                        // 3

  k_transpose<<<dim3((256 * 256 + 255) / 256), dim3(256), 0, stream>>>(a2w, a2wT, 256, 256);
  k_z2x<<<dim3(2048), dim3(256), 0, stream>>>(x, a2wT, a2b, a1b, z2h, xT);
  k_pack_a1<<<dim3(512), dim3(256), 0, stream>>>(a1w, a1p8);
  k_pack_whh<<<dim3(1024), dim3(256), 0, stream>>>(whh, whh8);
  k_wcomb<<<dim3(1024), dim3(320), 0, stream>>>(wih, tw, tb, bih, bhh, wc8, bcomb);
  k_whead<<<dim3(1), dim3(512), 0, stream>>>(f1w, f1b, f2w, f2b, whead, bhead);

  k_decoder<<<dim3(256), dim3(1024), 0, stream>>>(z2h, xT, y, a3w, a1p8, whh8, wc8,
                                                  bcomb, whead, bhead, out);
}

// Round 7
// 12127.161 us; speedup vs baseline: 1.0379x; 1.0169x over previous
//
#include <hip/hip_runtime.h>

// Decoder: B=256, T=128, ENC=256, DEC=256, OUT=3. All fp32 in/out.
//
// Round 7: escape the 64-VGPR trap two ways at once.
// r4-r6 post-mortem: regalloc targets 8 waves/EU (ignores that 158KB LDS
// forces 1 WG/CU), pinning VGPR=64; pipeline state spilled (WRITE_SIZE
// 6.29GB). r6's waves_per_eu attribute next to __launch_bounds__ was ignored
// (byte-identical binary).
//  (a) NO __launch_bounds__; only amdgpu_flat_work_group_size(1024,1024)
//      + amdgpu_waves_per_eu(4,4) -> budget 128 VGPR.
//  (b) depth-4 named register rotation (consume-then-reload, no arrays, no
//      cross-phase prefetch): peak live ~55-70 VGPR -> fits even a 64 cap.
// Predicted: WRITE_SIZE ~384KB (tripwire!), VGPR 84-128 if (a) works else 64,
// dur 1.5-1.75ms / 1.75-1.9ms respectively.

#define TT 128
#define SCL 2.885390081777927f  // 2*log2(e)

typedef _Float16 h2v __attribute__((ext_vector_type(2)));
typedef _Float16 f16x4 __attribute__((ext_vector_type(4)));
typedef _Float16 f16x8 __attribute__((ext_vector_type(8)));

__device__ __forceinline__ float fdot2(h2v a, h2v b, float c) {
#if __has_builtin(__builtin_amdgcn_fdot2)
  return __builtin_amdgcn_fdot2(a, b, c, false);
#else
  return c + (float)a[0] * (float)b[0] + (float)a[1] * (float)b[1];
#endif
}

__device__ __forceinline__ float exp2_fast(float x) {
#if __has_builtin(__builtin_amdgcn_exp2f)
  return __builtin_amdgcn_exp2f(x);
#else
  return exp2f(x);
#endif
}
__device__ __forceinline__ float rcp_fast(float x) {
#if __has_builtin(__builtin_amdgcn_rcpf)
  return __builtin_amdgcn_rcpf(x);
#else
  return 1.f / x;
#endif
}

__device__ __forceinline__ float tanh_scaled(float s) {  // s = SCL*v
  return fmaf(-2.f, rcp_fast(exp2_fast(s) + 1.f), 1.f);
}
__device__ __forceinline__ float fast_sig(float x) {
  return rcp_fast(1.f + __expf(-x));
}
__device__ __forceinline__ float fast_tanh(float x) {
  return tanh_scaled(x * SCL);
}

__device__ __forceinline__ float dot8(f16x8 w, f16x8 h, float acc) {
  h2v w0 = __builtin_shufflevector(w, w, 0, 1), h0 = __builtin_shufflevector(h, h, 0, 1);
  h2v w1 = __builtin_shufflevector(w, w, 2, 3), h1 = __builtin_shufflevector(h, h, 2, 3);
  h2v w2 = __builtin_shufflevector(w, w, 4, 5), h2 = __builtin_shufflevector(h, h, 4, 5);
  h2v w3 = __builtin_shufflevector(w, w, 6, 7), h3 = __builtin_shufflevector(h, h, 6, 7);
  acc = fdot2(w0, h0, acc);
  acc = fdot2(w1, h1, acc);
  acc = fdot2(w2, h2, acc);
  acc = fdot2(w3, h3, acc);
  return acc;
}

// consume wreg into acc, then refill wreg with the next chunk
#define DOT_RL(acc, wreg, opnd, nextload) \
  acc = dot8(wreg, opnd, acc);            \
  wreg = (nextload);

// ---------------- precompute kernels ----------------

__global__ void k_transpose(const float* __restrict__ src, float* __restrict__ dst,
                            int R, int C) {
  int idx = blockIdx.x * 256 + threadIdx.x;
  if (idx >= R * C) return;
  int r = idx / C, c = idx - r * C;
  dst[(size_t)c * R + r] = src[idx];
}

// z2h[row][f] = SCL*(sum_e x[row][e]*attn2_w[f][e] + a2b[f] + a1b[f]) fp16
// + emits xTg[b][e][t] fp16 via 2x f16x8 vector stores per thread.
__global__ __launch_bounds__(256) void k_z2x(const float* __restrict__ x,
                                             const float* __restrict__ a2wT,
                                             const float* __restrict__ a2b,
                                             const float* __restrict__ a1b,
                                             _Float16* __restrict__ z2h,
                                             _Float16* __restrict__ xTg) {
  __shared__ float xt[16][257];
  const int r0 = blockIdx.x * 16;
  const int tid = threadIdx.x;
  for (int idx = tid; idx < 16 * 256; idx += 256) {
    int rr = idx >> 8, e = idx & 255;
    xt[rr][e] = x[(size_t)(r0 + rr) * 256 + e];
  }
  __syncthreads();
  const int f = tid;
  float bias = a2b[f] + a1b[f];
  float acc[16];
#pragma unroll
  for (int rr = 0; rr < 16; ++rr) acc[rr] = bias;
  for (int e = 0; e < 256; ++e) {
    float w = a2wT[(size_t)e * 256 + f];
#pragma unroll
    for (int rr = 0; rr < 16; ++rr) acc[rr] += w * xt[rr][e];
  }
#pragma unroll
  for (int rr = 0; rr < 16; ++rr)
    z2h[(size_t)(r0 + rr) * 256 + f] = (_Float16)(acc[rr] * SCL);
  const int bb = r0 >> 7, t0 = r0 & 127;
  f16x8 lo, hi;
#pragma unroll
  for (int rr = 0; rr < 8; ++rr) lo[rr] = (_Float16)xt[rr][f];
#pragma unroll
  for (int rr = 0; rr < 8; ++rr) hi[rr] = (_Float16)xt[8 + rr][f];
  _Float16* d = &xTg[((size_t)bb * 256 + f) * 128 + t0];
  *(f16x8*)d = lo;
  *(f16x8*)(d + 8) = hi;
}

// a1p8[kc][f][8] = attn1_w[f][kc*8+j] * SCL   (kc<64, f<256)
__global__ void k_pack_a1(const float* __restrict__ a1w, _Float16* __restrict__ dst) {
  int idx = blockIdx.x * 256 + threadIdx.x;  // 131072
  int j = idx & 7, f = (idx >> 3) & 255, kc = idx >> 11;
  dst[idx] = (_Float16)(a1w[(size_t)f * 512 + kc * 8 + j] * SCL);
}

// whh8[kc][n][8] = w_hh[n][kc*8+j]   (kc<32, n<1024)
__global__ void k_pack_whh(const float* __restrict__ whh, _Float16* __restrict__ dst) {
  int idx = blockIdx.x * 256 + threadIdx.x;  // 262144
  int j = idx & 7, n = (idx >> 3) & 1023, kc = idx >> 13;
  dst[idx] = (_Float16)whh[(size_t)n * 256 + kc * 8 + j];
}

// wc8[kc][n][8] fp16 of (w_ih @ tilde_w)[n][kc*8+j], k>=259 zero-pad (kc<33)
__global__ __launch_bounds__(320) void k_wcomb(const float* __restrict__ w_ih,
                                               const float* __restrict__ tilde_w,
                                               const float* __restrict__ tilde_b,
                                               const float* __restrict__ b_ih,
                                               const float* __restrict__ b_hh,
                                               _Float16* __restrict__ wc8,
                                               float* __restrict__ bcomb) {
  __shared__ float wrow[512];
  __shared__ float bred[320];
  const int n = blockIdx.x;
  const int tid = threadIdx.x;
  for (int j = tid; j < 512; j += 320) wrow[j] = w_ih[(size_t)n * 512 + j];
  __syncthreads();
  if (tid < 264) {
    float acc = 0.f;
    if (tid < 259)
      for (int j = 0; j < 512; ++j) acc += wrow[j] * tilde_w[(size_t)j * 259 + tid];
    wc8[(size_t)(tid >> 3) * 8192 + n * 8 + (tid & 7)] = (_Float16)acc;
  }
  float p = 0.f;
  for (int j = tid; j < 512; j += 320) p += wrow[j] * tilde_b[j];
  bred[tid] = p;
  __syncthreads();
  if (tid == 0) {
    float s = 0.f;
    for (int j = 0; j < 320; ++j) s += bred[j];
    bcomb[n] = s + b_ih[n] + b_hh[n];
  }
}

// whead[o][k] = fc2_w @ fc1_w; bhead[o] = fc2_w[o]·fc1_b + fc2_b[o]
__global__ __launch_bounds__(512) void k_whead(const float* __restrict__ fc1_w,
                                               const float* __restrict__ fc1_b,
                                               const float* __restrict__ fc2_w,
                                               const float* __restrict__ fc2_b,
                                               float* __restrict__ whead,
                                               float* __restrict__ bhead) {
  const int k = threadIdx.x;
#pragma unroll
  for (int o = 0; o < 3; ++o) {
    float acc = 0.f;
    for (int j = 0; j < 256; ++j) acc += fc2_w[o * 256 + j] * fc1_w[(size_t)j * 512 + k];
    whead[o * 512 + k] = acc;
  }
  if (k < 3) {
    float acc = fc2_b[k];
    for (int j = 0; j < 256; ++j) acc += fc2_w[k * 256 + j] * fc1_b[j];
    bhead[k] = acc;
  }
}

// ---------------- main persistent decoder ----------------

__global__ __attribute__((amdgpu_flat_work_group_size(1024, 1024),
                          amdgpu_waves_per_eu(4, 4))) void k_decoder(
    const _Float16* __restrict__ z2g,  // [32768][256] fp16, pre-scaled, incl biases
    const _Float16* __restrict__ xTg,  // [256][256 e][128 t] fp16
    const float* __restrict__ yg,      // y_seq [256][128][3] fp32
    const float* __restrict__ a3w,     // [256]
    const _Float16* __restrict__ a1p8, // [64 kc][256 f][8]
    const _Float16* __restrict__ whh8, // [32 kc][1024 n][8]
    const _Float16* __restrict__ wc8,  // [33 kc][1024 n][8]
    const float* __restrict__ bcomb,   // [1024]
    const float* __restrict__ whead,   // [3][512]
    const float* __restrict__ bhead,   // [3]
    float* __restrict__ outg)          // [256][128][3]
{
  __shared__ __align__(16) _Float16 z2s[128][260];
  __shared__ __align__(16) _Float16 xs[256][132];
  __shared__ float zpart[1024];
  __shared__ float scpart[1024];
  __shared__ float cpart[1024];
  __shared__ float gbuf[1024];
  __shared__ float z1c[256];
  __shared__ float hbuf[256], cbuf[256], ctxs[256], w3s[256];
  __shared__ __align__(16) _Float16 hc8[512];  // [h(256); c(256)]
  __shared__ __align__(16) _Float16 u8[264];   // [y(3); ctx(256); pad0(5)]
  __shared__ float attv[128];
  __shared__ float sred[8];

  const int b = blockIdx.x;
  const int tid = threadIdx.x;

  // stage z2[b] -> [t][260], xT[b] -> [e][132]
  {
    const f16x8* zsrc = (const f16x8*)(z2g + (size_t)b * TT * 256);
    for (int c = tid; c < 4096; c += 1024) {
      int t = c >> 5, fc = c & 31;
      f16x8 v = zsrc[c];
      f16x4 lo = __builtin_shufflevector(v, v, 0, 1, 2, 3);
      f16x4 hi = __builtin_shufflevector(v, v, 4, 5, 6, 7);
      _Float16* d = &z2s[t][fc * 8];
      *(f16x4*)d = lo;
      *(f16x4*)(d + 4) = hi;
    }
    const f16x8* xsrc = (const f16x8*)(xTg + (size_t)b * 256 * 128);
    for (int c = tid; c < 4096; c += 1024) {
      int e = c >> 4, tc = c & 15;
      f16x8 v = xsrc[c];
      f16x4 lo = __builtin_shufflevector(v, v, 0, 1, 2, 3);
      f16x4 hi = __builtin_shufflevector(v, v, 4, 5, 6, 7);
      _Float16* d = &xs[e][tc * 8];
      *(f16x4*)d = lo;
      *(f16x4*)(d + 4) = hi;
    }
  }
  if (tid < 256) {
    w3s[tid] = a3w[tid];
    hbuf[tid] = 0.f; cbuf[tid] = 0.f;
    hc8[tid] = (_Float16)0.f; hc8[256 + tid] = (_Float16)0.f;
  }
  if (tid >= 259 && tid < 264) u8[tid] = (_Float16)0.f;
  __syncthreads();  // B0

  const int f_z = tid & 255;
  const int qz = tid >> 8;  // k-quarter for z1 (wave-uniform)
  const f16x8* pa = (const f16x8*)a1p8 + ((size_t)(qz * 16) * 256 + f_z);
  const f16x8* pw = (const f16x8*)whh8 + tid;
  const f16x8* pc = (const f16x8*)wc8 + tid;
  const f16x8* hc8v = (const f16x8*)hc8;
  const f16x8* u8v = (const f16x8*)u8;
  const float bc = bcomb[tid];

#define HZ(i) hc8v[qz * 16 + (i)]
#define HH(i) hc8v[(i)]
#define UU(i) u8v[(i)]

  // head weights resident in registers
  float whr[8], bh = 0.f;
  if (tid < 192) {
    int o = tid >> 6, lane = tid & 63;
#pragma unroll
    for (int q2 = 0; q2 < 8; ++q2) whr[q2] = whead[o * 512 + lane + (q2 << 6)];
    bh = bhead[o];
  }

  for (int t = 0; t < TT; ++t) {
    float yreg = (tid < 3) ? yg[(size_t)(b * TT + t) * 3 + tid] : 0.f;

    // ---- Phase Z: z1 partials (4-way k-split) + gates_h (n = tid)
    float ghr;
    {
      // a1: 16 chunks, depth-4 rotation
      f16x8 w0 = pa[(size_t)0 * 256], w1 = pa[(size_t)1 * 256],
            w2 = pa[(size_t)2 * 256], w3 = pa[(size_t)3 * 256];
      float za0 = 0.f, za1 = 0.f, za2 = 0.f, za3 = 0.f;
      DOT_RL(za0, w0, HZ(0), pa[(size_t)4 * 256]);
      DOT_RL(za1, w1, HZ(1), pa[(size_t)5 * 256]);
      DOT_RL(za2, w2, HZ(2), pa[(size_t)6 * 256]);
      DOT_RL(za3, w3, HZ(3), pa[(size_t)7 * 256]);
      DOT_RL(za0, w0, HZ(4), pa[(size_t)8 * 256]);
      DOT_RL(za1, w1, HZ(5), pa[(size_t)9 * 256]);
      DOT_RL(za2, w2, HZ(6), pa[(size_t)10 * 256]);
      DOT_RL(za3, w3, HZ(7), pa[(size_t)11 * 256]);
      DOT_RL(za0, w0, HZ(8), pa[(size_t)12 * 256]);
      DOT_RL(za1, w1, HZ(9), pa[(size_t)13 * 256]);
      DOT_RL(za2, w2, HZ(10), pa[(size_t)14 * 256]);
      DOT_RL(za3, w3, HZ(11), pa[(size_t)15 * 256]);
      za0 = dot8(w0, HZ(12), za0);
      za1 = dot8(w1, HZ(13), za1);
      za2 = dot8(w2, HZ(14), za2);
      za3 = dot8(w3, HZ(15), za3);
      zpart[tid] = (za0 + za1) + (za2 + za3);

      // whh: 32 chunks, depth-4 rotation
      f16x8 v0 = pw[(size_t)0 * 1024], v1 = pw[(size_t)1 * 1024],
            v2 = pw[(size_t)2 * 1024], v3 = pw[(size_t)3 * 1024];
      float g0 = 0.f, g1 = 0.f, g2 = 0.f, g3 = 0.f;
      DOT_RL(g0, v0, HH(0), pw[(size_t)4 * 1024]);
      DOT_RL(g1, v1, HH(1), pw[(size_t)5 * 1024]);
      DOT_RL(g2, v2, HH(2), pw[(size_t)6 * 1024]);
      DOT_RL(g3, v3, HH(3), pw[(size_t)7 * 1024]);
      DOT_RL(g0, v0, HH(4), pw[(size_t)8 * 1024]);
      DOT_RL(g1, v1, HH(5), pw[(size_t)9 * 1024]);
      DOT_RL(g2, v2, HH(6), pw[(size_t)10 * 1024]);
      DOT_RL(g3, v3, HH(7), pw[(size_t)11 * 1024]);
      DOT_RL(g0, v0, HH(8), pw[(size_t)12 * 1024]);
      DOT_RL(g1, v1, HH(9), pw[(size_t)13 * 1024]);
      DOT_RL(g2, v2, HH(10), pw[(size_t)14 * 1024]);
      DOT_RL(g3, v3, HH(11), pw[(size_t)15 * 1024]);
      DOT_RL(g0, v0, HH(12), pw[(size_t)16 * 1024]);
      DOT_RL(g1, v1, HH(13), pw[(size_t)17 * 1024]);
      DOT_RL(g2, v2, HH(14), pw[(size_t)18 * 1024]);
      DOT_RL(g3, v3, HH(15), pw[(size_t)19 * 1024]);
      DOT_RL(g0, v0, HH(16), pw[(size_t)20 * 1024]);
      DOT_RL(g1, v1, HH(17), pw[(size_t)21 * 1024]);
      DOT_RL(g2, v2, HH(18), pw[(size_t)22 * 1024]);
      DOT_RL(g3, v3, HH(19), pw[(size_t)23 * 1024]);
      DOT_RL(g0, v0, HH(20), pw[(size_t)24 * 1024]);
      DOT_RL(g1, v1, HH(21), pw[(size_t)25 * 1024]);
      DOT_RL(g2, v2, HH(22), pw[(size_t)26 * 1024]);
      DOT_RL(g3, v3, HH(23), pw[(size_t)27 * 1024]);
      DOT_RL(g0, v0, HH(24), pw[(size_t)28 * 1024]);
      DOT_RL(g1, v1, HH(25), pw[(size_t)29 * 1024]);
      DOT_RL(g2, v2, HH(26), pw[(size_t)30 * 1024]);
      DOT_RL(g3, v3, HH(27), pw[(size_t)31 * 1024]);
      g0 = dot8(v0, HH(28), g0);
      g1 = dot8(v1, HH(29), g1);
      g2 = dot8(v2, HH(30), g2);
      g3 = dot8(v3, HH(31), g3);
      ghr = (g0 + g1) + (g2 + g3);
    }
    __syncthreads();  // B1

    if (tid < 256)
      z1c[tid] = zpart[tid] + zpart[tid + 256] + zpart[tid + 512] + zpart[tid + 768];
    __syncthreads();  // B2

    // ---- Phase S: scores; tp = tid&127, q = tid>>7 (8 groups x 32 f)
    {
      int tp = tid & 127, q = tid >> 7, f0 = q * 32;
      const _Float16* zr = &z2s[tp][f0];
      float acc = 0.f;
#pragma unroll
      for (int i = 0; i < 8; ++i) {
        f16x4 zz = *(const f16x4*)(zr + i * 4);
#pragma unroll
        for (int j = 0; j < 4; ++j) {
          int f = f0 + i * 4 + j;
          acc = fmaf(tanh_scaled(z1c[f] + (float)zz[j]), w3s[f], acc);
        }
      }
      scpart[tid] = acc;
    }
    __syncthreads();  // B3

    // ---- softmax (no max-sub: |score| <= sum|w3| ~ 25 << 88)
    if (tid < 128) {
      float sc = scpart[tid] + scpart[tid + 128] + scpart[tid + 256] + scpart[tid + 384] +
                 scpart[tid + 512] + scpart[tid + 640] + scpart[tid + 768] + scpart[tid + 896];
      float e = __expf(sc);
      attv[tid] = e;
      float s = e;
#pragma unroll
      for (int off = 32; off > 0; off >>= 1) s += __shfl_xor(s, off);
      if ((tid & 63) == 0) sred[2 + (tid >> 6)] = s;
    }
    __syncthreads();  // B4

    // ---- Phase C: context partials; e = tid&255, th4 = tid>>8 (4 x 32 t)
    {
      int e = tid & 255, th4 = tid >> 8;
      const _Float16* xr = &xs[e][th4 * 32];
      float acc = 0.f;
#pragma unroll
      for (int i = 0; i < 8; ++i) {
        f16x4 xv = *(const f16x4*)(xr + i * 4);
#pragma unroll
        for (int j = 0; j < 4; ++j)
          acc = fmaf(attv[th4 * 32 + i * 4 + j], (float)xv[j], acc);
      }
      cpart[tid] = acc;
    }
    __syncthreads();  // B5

    const float rsum = rcp_fast(sred[2] + sred[3]);
    if (tid < 256) {
      float cv = (cpart[tid] + cpart[tid + 256] + cpart[tid + 512] + cpart[tid + 768]) * rsum;
      ctxs[tid] = cv;
      u8[3 + tid] = (_Float16)cv;
    }
    if (tid < 3) u8[tid] = (_Float16)yreg;
    __syncthreads();  // B6

    // ---- Phase G: gates = W_comb·u + gates_h + b_comb (n = tid)
    {
      f16x8 v0 = pc[(size_t)0 * 1024], v1 = pc[(size_t)1 * 1024],
            v2 = pc[(size_t)2 * 1024], v3 = pc[(size_t)3 * 1024];
      float a0 = 0.f, a1 = 0.f, a2 = 0.f, a3 = 0.f;
      DOT_RL(a0, v0, UU(0), pc[(size_t)4 * 1024]);
      DOT_RL(a1, v1, UU(1), pc[(size_t)5 * 1024]);
      DOT_RL(a2, v2, UU(2), pc[(size_t)6 * 1024]);
      DOT_RL(a3, v3, UU(3), pc[(size_t)7 * 1024]);
      DOT_RL(a0, v0, UU(4), pc[(size_t)8 * 1024]);
      DOT_RL(a1, v1, UU(5), pc[(size_t)9 * 1024]);
      DOT_RL(a2, v2, UU(6), pc[(size_t)10 * 1024]);
      DOT_RL(a3, v3, UU(7), pc[(size_t)11 * 1024]);
      DOT_RL(a0, v0, UU(8), pc[(size_t)12 * 1024]);
      DOT_RL(a1, v1, UU(9), pc[(size_t)13 * 1024]);
      DOT_RL(a2, v2, UU(10), pc[(size_t)14 * 1024]);
      DOT_RL(a3, v3, UU(11), pc[(size_t)15 * 1024]);
      DOT_RL(a0, v0, UU(12), pc[(size_t)16 * 1024]);
      DOT_RL(a1, v1, UU(13), pc[(size_t)17 * 1024]);
      DOT_RL(a2, v2, UU(14), pc[(size_t)18 * 1024]);
      DOT_RL(a3, v3, UU(15), pc[(size_t)19 * 1024]);
      DOT_RL(a0, v0, UU(16), pc[(size_t)20 * 1024]);
      DOT_RL(a1, v1, UU(17), pc[(size_t)21 * 1024]);
      DOT_RL(a2, v2, UU(18), pc[(size_t)22 * 1024]);
      DOT_RL(a3, v3, UU(19), pc[(size_t)23 * 1024]);
      DOT_RL(a0, v0, UU(20), pc[(size_t)24 * 1024]);
      DOT_RL(a1, v1, UU(21), pc[(size_t)25 * 1024]);
      DOT_RL(a2, v2, UU(22), pc[(size_t)26 * 1024]);
      DOT_RL(a3, v3, UU(23), pc[(size_t)27 * 1024]);
      DOT_RL(a0, v0, UU(24), pc[(size_t)28 * 1024]);
      DOT_RL(a1, v1, UU(25), pc[(size_t)29 * 1024]);
      DOT_RL(a2, v2, UU(26), pc[(size_t)30 * 1024]);
      DOT_RL(a3, v3, UU(27), pc[(size_t)31 * 1024]);
      DOT_RL(a0, v0, UU(28), pc[(size_t)32 * 1024]);
      a1 = dot8(v1, UU(29), a1);
      a2 = dot8(v2, UU(30), a2);
      a3 = dot8(v3, UU(31), a3);
      a0 = dot8(v0, UU(32), a0);
      gbuf[tid] = (a0 + a1) + (a2 + a3) + ghr + bc;
    }
    __syncthreads();  // B7

    // ---- LSTM pointwise
    if (tid < 256) {
      float gi = gbuf[tid], gf = gbuf[tid + 256], gg = gbuf[tid + 512], go = gbuf[tid + 768];
      float cn = fast_sig(gf) * cbuf[tid] + fast_sig(gi) * fast_tanh(gg);
      float hn = fast_sig(go) * fast_tanh(cn);
      if (t < TT - 1) {  // reference skips state update on last step
        hbuf[tid] = hn; cbuf[tid] = cn;
        hc8[tid] = (_Float16)hn; hc8[256 + tid] = (_Float16)cn;
      }
    }
    __syncthreads();  // B8

    // ---- Phase H: out[b,t,o] = W_head[o]·[h2, ctx] + b_head[o]
    if (tid < 192) {
      int o = tid >> 6, lane = tid & 63;
      float acc = 0.f;
#pragma unroll
      for (int q2 = 0; q2 < 8; ++q2) {
        int k = lane + (q2 << 6);
        float v = (k < 256) ? hbuf[k] : ctxs[k - 256];
        acc = fmaf(whr[q2], v, acc);
      }
#pragma unroll
      for (int off = 32; off > 0; off >>= 1) acc += __shfl_xor(acc, off);
      if (lane == 0) outg[(size_t)(b * TT + t) * 3 + o] = acc + bh;
    }
    // no barrier: next phase writes only zpart (disjoint from hbuf/ctxs)
  }
#undef HZ
#undef HH
#undef UU
}

// ---------------- launch ----------------

extern "C" void kernel_launch(void* const* d_in, const int* in_sizes, int n_in,
                              void* d_out, int out_size, void* d_ws, size_t ws_size,
                              hipStream_t stream) {
  const float* x   = (const float*)d_in[0];
  const float* y   = (const float*)d_in[1];
  const float* a1w = (const float*)d_in[2];
  const float* a1b = (const float*)d_in[3];
  const float* a2w = (const float*)d_in[4];
  const float* a2b = (const float*)d_in[5];
  const float* a3w = (const float*)d_in[6];
  // d_in[7] = attn3_b: softmax-invariant constant, skipped
  const float* tw  = (const float*)d_in[8];
  const float* tb  = (const float*)d_in[9];
  const float* wih = (const float*)d_in[10];
  const float* whh = (const float*)d_in[11];
  const float* bih = (const float*)d_in[12];
  const float* bhh = (const float*)d_in[13];
  const float* f1w = (const float*)d_in[14];
  const float* f1b = (const float*)d_in[15];
  const float* f2w = (const float*)d_in[16];
  const float* f2b = (const float*)d_in[17];
  float* out = (float*)d_out;

  float* ws = (float*)d_ws;
  _Float16* z2h  = (_Float16*)ws;                       // 8,388,608 h = 4,194,304 f
  _Float16* xT   = (_Float16*)(ws + 4194304);           // 8,388,608 h
  float* a2wT    = ws + 8388608;                        // 65,536 f
  _Float16* a1p8 = (_Float16*)(ws + 8388608 + 65536);   // 131,072 h
  _Float16* whh8 = (_Float16*)(ws + 8388608 + 131072);  // 262,144 h
  _Float16* wc8  = (_Float16*)(ws + 8388608 + 262144);  // 270,336 h
  float* bcomb   = ws + 8388608 + 262144 + 135168;      // 1,024
  float* whead   = bcomb + 1024;                        // 1,536
  float* bhead   = whead + 1536;                        // 3

  k_transpose<<<dim3((256 * 256 + 255) / 256), dim3(256), 0, stream>>>(a2w, a2wT, 256, 256);
  k_z2x<<<dim3(2048), dim3(256), 0, stream>>>(x, a2wT, a2b, a1b, z2h, xT);
  k_pack_a1<<<dim3(512), dim3(256), 0, stream>>>(a1w, a1p8);
  k_pack_whh<<<dim3(1024), dim3(256), 0, stream>>>(whh, whh8);
  k_wcomb<<<dim3(1024), dim3(320), 0, stream>>>(wih, tw, tb, bih, bhh, wc8, bcomb);
  k_whead<<<dim3(1), dim3(512), 0, stream>>>(f1w, f1b, f2w, f2b, whead, bhead);

  k_decoder<<<dim3(256), dim3(1024), 0, stream>>>(z2h, xT, y, a3w, a1p8, whh8, wc8,
                                                  bcomb, whead, bhead, out);
}

// Round 8
// 1884.360 us; speedup vs baseline: 6.6797x; 6.4357x over previous
//
#include <hip/hip_runtime.h>

// Decoder: B=256, T=128, ENC=256, DEC=256, OUT=3. All fp32 in/out.
//
// Round 8: RESTORE of the round-3 kernel (proven 1.889 ms, WRITE_SIZE 384 KB)
// + round-4's vectorized k_z2x emit (separate kernel, not involved in spill).
// Rounds 4-7 post-mortem: every manually-unrolled deep-pipeline variant of the
// stream phases spilled ~192 B/thread/step to scratch (WRITE_SIZE 6.29 GB,
// FETCH 25 GB, VGPR pinned 64) regardless of arrays vs named regs, depth 8 vs
// 4, launch-bounds vs waves_per_eu attributes. Round 3's compact
// #pragma-unroll-4 loops at the same VGPR_Count=64 do NOT spill (short live
// ranges). Lesson recorded: on this compiler, keep stream loops compact; do
// not hand-unroll long dependency webs.
// Structure floor: weight stream 1.29 MB/step/WG at ~134 GB/s per-CU L2 BW
// (~9.6 us) + VALU ~6.3 us, partial overlap -> ~14.75 us/step = ~1.89 ms.

#define TT 128
#define SCL 2.885390081777927f  // 2*log2(e)

typedef _Float16 h2v __attribute__((ext_vector_type(2)));
typedef _Float16 f16x4 __attribute__((ext_vector_type(4)));
typedef _Float16 f16x8 __attribute__((ext_vector_type(8)));

__device__ __forceinline__ float fdot2(h2v a, h2v b, float c) {
#if __has_builtin(__builtin_amdgcn_fdot2)
  return __builtin_amdgcn_fdot2(a, b, c, false);
#else
  return c + (float)a[0] * (float)b[0] + (float)a[1] * (float)b[1];
#endif
}

__device__ __forceinline__ float exp2_fast(float x) {
#if __has_builtin(__builtin_amdgcn_exp2f)
  return __builtin_amdgcn_exp2f(x);
#else
  return exp2f(x);
#endif
}
__device__ __forceinline__ float rcp_fast(float x) {
#if __has_builtin(__builtin_amdgcn_rcpf)
  return __builtin_amdgcn_rcpf(x);
#else
  return 1.f / x;
#endif
}

// tanh(v) given s = SCL*v: 1 - 2/(exp2(s)+1). Saturates correctly via rcp(inf)=0.
__device__ __forceinline__ float tanh_scaled(float s) {
  return fmaf(-2.f, rcp_fast(exp2_fast(s) + 1.f), 1.f);
}
__device__ __forceinline__ float fast_sig(float x) {
  return rcp_fast(1.f + __expf(-x));
}
__device__ __forceinline__ float fast_tanh(float x) {
  return tanh_scaled(x * SCL);
}

__device__ __forceinline__ float dot8(f16x8 w, f16x8 h, float acc) {
  h2v w0 = __builtin_shufflevector(w, w, 0, 1), h0 = __builtin_shufflevector(h, h, 0, 1);
  h2v w1 = __builtin_shufflevector(w, w, 2, 3), h1 = __builtin_shufflevector(h, h, 2, 3);
  h2v w2 = __builtin_shufflevector(w, w, 4, 5), h2 = __builtin_shufflevector(h, h, 4, 5);
  h2v w3 = __builtin_shufflevector(w, w, 6, 7), h3 = __builtin_shufflevector(h, h, 6, 7);
  acc = fdot2(w0, h0, acc);
  acc = fdot2(w1, h1, acc);
  acc = fdot2(w2, h2, acc);
  acc = fdot2(w3, h3, acc);
  return acc;
}

// ---------------- precompute kernels ----------------

// fp32 transpose (attn2_w): dst[c*R + r] = src[r*C + c]
__global__ void k_transpose(const float* __restrict__ src, float* __restrict__ dst,
                            int R, int C) {
  int idx = blockIdx.x * 256 + threadIdx.x;
  if (idx >= R * C) return;
  int r = idx / C, c = idx - r * C;
  dst[(size_t)c * R + r] = src[idx];
}

// z2h[row][f] = SCL*(sum_e x[row][e]*attn2_w[f][e] + a2b[f] + a1b[f]) fp16
// + emits xTg[b][e][t] fp16 via 2x f16x8 vector stores per thread.
__global__ __launch_bounds__(256) void k_z2x(const float* __restrict__ x,
                                             const float* __restrict__ a2wT,
                                             const float* __restrict__ a2b,
                                             const float* __restrict__ a1b,
                                             _Float16* __restrict__ z2h,
                                             _Float16* __restrict__ xTg) {
  __shared__ float xt[16][257];
  const int r0 = blockIdx.x * 16;
  const int tid = threadIdx.x;
  for (int idx = tid; idx < 16 * 256; idx += 256) {
    int rr = idx >> 8, e = idx & 255;
    xt[rr][e] = x[(size_t)(r0 + rr) * 256 + e];
  }
  __syncthreads();
  const int f = tid;
  float bias = a2b[f] + a1b[f];
  float acc[16];
#pragma unroll
  for (int rr = 0; rr < 16; ++rr) acc[rr] = bias;
  for (int e = 0; e < 256; ++e) {
    float w = a2wT[(size_t)e * 256 + f];
#pragma unroll
    for (int rr = 0; rr < 16; ++rr) acc[rr] += w * xt[rr][e];
  }
#pragma unroll
  for (int rr = 0; rr < 16; ++rr)
    z2h[(size_t)(r0 + rr) * 256 + f] = (_Float16)(acc[rr] * SCL);
  // xT emit: thread owns column e=f; 16 contiguous t-halves = 2 f16x8 stores
  const int bb = r0 >> 7, t0 = r0 & 127;
  f16x8 lo, hi;
#pragma unroll
  for (int rr = 0; rr < 8; ++rr) lo[rr] = (_Float16)xt[rr][f];
#pragma unroll
  for (int rr = 0; rr < 8; ++rr) hi[rr] = (_Float16)xt[8 + rr][f];
  _Float16* d = &xTg[((size_t)bb * 256 + f) * 128 + t0];
  *(f16x8*)d = lo;
  *(f16x8*)(d + 8) = hi;
}

// a1p8[kc][f][8] = attn1_w[f][kc*8+j] * SCL   (kc<64, f<256)
__global__ void k_pack_a1(const float* __restrict__ a1w, _Float16* __restrict__ dst) {
  int idx = blockIdx.x * 256 + threadIdx.x;  // 131072
  int j = idx & 7, f = (idx >> 3) & 255, kc = idx >> 11;
  dst[idx] = (_Float16)(a1w[(size_t)f * 512 + kc * 8 + j] * SCL);
}

// whh8[kc][n][8] = w_hh[n][kc*8+j]   (kc<32, n<1024)
__global__ void k_pack_whh(const float* __restrict__ whh, _Float16* __restrict__ dst) {
  int idx = blockIdx.x * 256 + threadIdx.x;  // 262144
  int j = idx & 7, n = (idx >> 3) & 1023, kc = idx >> 13;
  dst[idx] = (_Float16)whh[(size_t)n * 256 + kc * 8 + j];
}

// wc8[kc][n][8] fp16 of (w_ih @ tilde_w)[n][kc*8+j], k>=259 zero-padded (kc<33)
// bcomb[n] = w_ih[n]·tilde_b + b_ih[n] + b_hh[n]
__global__ __launch_bounds__(320) void k_wcomb(const float* __restrict__ w_ih,
                                               const float* __restrict__ tilde_w,
                                               const float* __restrict__ tilde_b,
                                               const float* __restrict__ b_ih,
                                               const float* __restrict__ b_hh,
                                               _Float16* __restrict__ wc8,
                                               float* __restrict__ bcomb) {
  __shared__ float wrow[512];
  __shared__ float bred[320];
  const int n = blockIdx.x;
  const int tid = threadIdx.x;
  for (int j = tid; j < 512; j += 320) wrow[j] = w_ih[(size_t)n * 512 + j];
  __syncthreads();
  if (tid < 264) {
    float acc = 0.f;
    if (tid < 259)
      for (int j = 0; j < 512; ++j) acc += wrow[j] * tilde_w[(size_t)j * 259 + tid];
    wc8[(size_t)(tid >> 3) * 8192 + n * 8 + (tid & 7)] = (_Float16)acc;
  }
  float p = 0.f;
  for (int j = tid; j < 512; j += 320) p += wrow[j] * tilde_b[j];
  bred[tid] = p;
  __syncthreads();
  if (tid == 0) {
    float s = 0.f;
    for (int j = 0; j < 320; ++j) s += bred[j];
    bcomb[n] = s + b_ih[n] + b_hh[n];
  }
}

// whead[o][k] = fc2_w @ fc1_w; bhead[o] = fc2_w[o]·fc1_b + fc2_b[o]
__global__ __launch_bounds__(512) void k_whead(const float* __restrict__ fc1_w,
                                               const float* __restrict__ fc1_b,
                                               const float* __restrict__ fc2_w,
                                               const float* __restrict__ fc2_b,
                                               float* __restrict__ whead,
                                               float* __restrict__ bhead) {
  const int k = threadIdx.x;
#pragma unroll
  for (int o = 0; o < 3; ++o) {
    float acc = 0.f;
    for (int j = 0; j < 256; ++j) acc += fc2_w[o * 256 + j] * fc1_w[(size_t)j * 512 + k];
    whead[o * 512 + k] = acc;
  }
  if (k < 3) {
    float acc = fc2_b[k];
    for (int j = 0; j < 256; ++j) acc += fc2_w[k * 256 + j] * fc1_b[j];
    bhead[k] = acc;
  }
}

// ---------------- main persistent decoder ----------------

__global__ __launch_bounds__(1024, 4) void k_decoder(
    const _Float16* __restrict__ z2g,  // [32768][256] fp16, pre-scaled, incl biases
    const _Float16* __restrict__ xTg,  // [256][256 e][128 t] fp16
    const float* __restrict__ yg,      // y_seq [256][128][3] fp32
    const float* __restrict__ a3w,     // [256]
    const _Float16* __restrict__ a1p8, // [64 kc][256 f][8]
    const _Float16* __restrict__ whh8, // [32 kc][1024 n][8]
    const _Float16* __restrict__ wc8,  // [33 kc][1024 n][8]
    const float* __restrict__ bcomb,   // [1024]
    const float* __restrict__ whead,   // [3][512]
    const float* __restrict__ bhead,   // [3]
    float* __restrict__ outg)          // [256][128][3]
{
  __shared__ __align__(16) _Float16 z2s[128][260];  // 66,560 B
  __shared__ __align__(16) _Float16 xs[256][132];   // 67,584 B (transposed x)
  __shared__ float zpart[1024];
  __shared__ float scpart[1024];
  __shared__ float cpart[1024];
  __shared__ float gbuf[1024];
  __shared__ float z1c[256];
  __shared__ float hbuf[256], cbuf[256], ctxs[256], w3s[256];
  __shared__ __align__(16) _Float16 hc8[512];  // [h(256); c(256)]
  __shared__ __align__(16) _Float16 u8[264];   // [y(3); ctx(256); pad0(5)]
  __shared__ float attv[128];
  __shared__ float sred[8];

  const int b = blockIdx.x;
  const int tid = threadIdx.x;

  // stage z2[b] -> [t][260], xT[b] -> [e][132]
  {
    const f16x8* zsrc = (const f16x8*)(z2g + (size_t)b * TT * 256);
    for (int c = tid; c < 4096; c += 1024) {
      int t = c >> 5, fc = c & 31;
      f16x8 v = zsrc[c];
      f16x4 lo = __builtin_shufflevector(v, v, 0, 1, 2, 3);
      f16x4 hi = __builtin_shufflevector(v, v, 4, 5, 6, 7);
      _Float16* d = &z2s[t][fc * 8];
      *(f16x4*)d = lo;
      *(f16x4*)(d + 4) = hi;
    }
    const f16x8* xsrc = (const f16x8*)(xTg + (size_t)b * 256 * 128);
    for (int c = tid; c < 4096; c += 1024) {
      int e = c >> 4, tc = c & 15;
      f16x8 v = xsrc[c];
      f16x4 lo = __builtin_shufflevector(v, v, 0, 1, 2, 3);
      f16x4 hi = __builtin_shufflevector(v, v, 4, 5, 6, 7);
      _Float16* d = &xs[e][tc * 8];
      *(f16x4*)d = lo;
      *(f16x4*)(d + 4) = hi;
    }
  }
  if (tid < 256) {
    w3s[tid] = a3w[tid];
    hbuf[tid] = 0.f; cbuf[tid] = 0.f;
    hc8[tid] = (_Float16)0.f; hc8[256 + tid] = (_Float16)0.f;
  }
  if (tid >= 259 && tid < 264) u8[tid] = (_Float16)0.f;
  __syncthreads();  // B0

  const int f_z = tid & 255;
  const int qz = tid >> 8;  // k-quarter for z1
  const _Float16* pa = a1p8 + ((size_t)(qz * 16) * 256 + f_z) * 8;
  const _Float16* pw = whh8 + (size_t)tid * 8;
  const _Float16* pc = wc8 + (size_t)tid * 8;
  const float bc = bcomb[tid];

  // preload head weights (per-thread fixed)
  float whr[8], bh = 0.f;
  if (tid < 192) {
    int o = tid >> 6, lane = tid & 63;
#pragma unroll
    for (int q2 = 0; q2 < 8; ++q2) whr[q2] = whead[o * 512 + lane + (q2 << 6)];
    bh = bhead[o];
  }

  for (int t = 0; t < TT; ++t) {
    float yreg = (tid < 3) ? yg[(size_t)(b * TT + t) * 3 + tid] : 0.f;

    // ---- Phase Z: z1 partials (4-way k-split) + gates_h (n = tid)
    // NOTE: compact unroll-4 loops only. Hand-unrolled deep pipelines here
    // caused 6.3 GB/dispatch scratch spill in r4-r7 — do not reintroduce.
    float ghr;
    {
      float za0 = 0.f, za1 = 0.f;
#pragma unroll 4
      for (int i = 0; i < 16; i += 2) {
        f16x8 w0 = *(const f16x8*)(pa + (size_t)i * 2048);
        f16x8 w1 = *(const f16x8*)(pa + (size_t)(i + 1) * 2048);
        f16x8 h0 = *(const f16x8*)&hc8[(qz * 16 + i) * 8];
        f16x8 h1 = *(const f16x8*)&hc8[(qz * 16 + i + 1) * 8];
        za0 = dot8(w0, h0, za0);
        za1 = dot8(w1, h1, za1);
      }
      zpart[tid] = za0 + za1;
      float g0 = 0.f, g1 = 0.f;
#pragma unroll 4
      for (int kc = 0; kc < 32; kc += 2) {
        f16x8 w0 = *(const f16x8*)(pw + (size_t)kc * 8192);
        f16x8 w1 = *(const f16x8*)(pw + (size_t)(kc + 1) * 8192);
        f16x8 h0 = *(const f16x8*)&hc8[kc * 8];
        f16x8 h1 = *(const f16x8*)&hc8[(kc + 1) * 8];
        g0 = dot8(w0, h0, g0);
        g1 = dot8(w1, h1, g1);
      }
      ghr = g0 + g1;
    }
    __syncthreads();  // B1

    if (tid < 256)
      z1c[tid] = zpart[tid] + zpart[tid + 256] + zpart[tid + 512] + zpart[tid + 768];
    __syncthreads();  // B2

    // ---- Phase S: scores; tp = tid&127, q = tid>>7 (8 groups x 32 f)
    {
      int tp = tid & 127, q = tid >> 7, f0 = q * 32;
      const _Float16* zr = &z2s[tp][f0];
      float acc = 0.f;
#pragma unroll
      for (int i = 0; i < 8; ++i) {
        f16x4 zz = *(const f16x4*)(zr + i * 4);
#pragma unroll
        for (int j = 0; j < 4; ++j) {
          int f = f0 + i * 4 + j;
          acc = fmaf(tanh_scaled(z1c[f] + (float)zz[j]), w3s[f], acc);
        }
      }
      scpart[tid] = acc;
    }
    __syncthreads();  // B3

    // ---- softmax (no max-sub: |score| <= sum|w3| ~ 25 << 88)
    if (tid < 128) {
      float sc = scpart[tid] + scpart[tid + 128] + scpart[tid + 256] + scpart[tid + 384] +
                 scpart[tid + 512] + scpart[tid + 640] + scpart[tid + 768] + scpart[tid + 896];
      float e = __expf(sc);
      attv[tid] = e;
      float s = e;
#pragma unroll
      for (int off = 32; off > 0; off >>= 1) s += __shfl_xor(s, off);
      if ((tid & 63) == 0) sred[2 + (tid >> 6)] = s;
    }
    __syncthreads();  // B4

    // ---- Phase C: context partials; e = tid&255, th4 = tid>>8 (4 x 32 t)
    {
      int e = tid & 255, th4 = tid >> 8;
      const _Float16* xr = &xs[e][th4 * 32];
      float acc = 0.f;
#pragma unroll
      for (int i = 0; i < 8; ++i) {
        f16x4 xv = *(const f16x4*)(xr + i * 4);
#pragma unroll
        for (int j = 0; j < 4; ++j)
          acc = fmaf(attv[th4 * 32 + i * 4 + j], (float)xv[j], acc);
      }
      cpart[tid] = acc;
    }
    __syncthreads();  // B5

    const float rsum = rcp_fast(sred[2] + sred[3]);
    if (tid < 256) {
      float cv = (cpart[tid] + cpart[tid + 256] + cpart[tid + 512] + cpart[tid + 768]) * rsum;
      ctxs[tid] = cv;
      u8[3 + tid] = (_Float16)cv;
    }
    if (tid < 3) u8[tid] = (_Float16)yreg;
    __syncthreads();  // B6

    // ---- Phase G: gates = W_comb·u + gates_h + b_comb (n = tid)
    {
      float a0 = 0.f, a1 = 0.f;
#pragma unroll 4
      for (int kc = 0; kc < 32; kc += 2) {
        f16x8 w0 = *(const f16x8*)(pc + (size_t)kc * 8192);
        f16x8 w1 = *(const f16x8*)(pc + (size_t)(kc + 1) * 8192);
        f16x8 u0 = *(const f16x8*)&u8[kc * 8];
        f16x8 u1 = *(const f16x8*)&u8[(kc + 1) * 8];
        a0 = dot8(w0, u0, a0);
        a1 = dot8(w1, u1, a1);
      }
      a0 = dot8(*(const f16x8*)(pc + (size_t)32 * 8192), *(const f16x8*)&u8[256], a0);
      gbuf[tid] = a0 + a1 + ghr + bc;
    }
    __syncthreads();  // B7

    // ---- LSTM pointwise
    if (tid < 256) {
      float gi = gbuf[tid], gf = gbuf[tid + 256], gg = gbuf[tid + 512], go = gbuf[tid + 768];
      float cn = fast_sig(gf) * cbuf[tid] + fast_sig(gi) * fast_tanh(gg);
      float hn = fast_sig(go) * fast_tanh(cn);
      if (t < TT - 1) {  // reference skips state update on last step
        hbuf[tid] = hn; cbuf[tid] = cn;
        hc8[tid] = (_Float16)hn; hc8[256 + tid] = (_Float16)cn;
      }
    }
    __syncthreads();  // B8

    // ---- Phase H: out[b,t,o] = W_head[o]·[h2, ctx] + b_head[o]
    if (tid < 192) {
      int o = tid >> 6, lane = tid & 63;
      float acc = 0.f;
#pragma unroll
      for (int q2 = 0; q2 < 8; ++q2) {
        int k = lane + (q2 << 6);
        float v = (k < 256) ? hbuf[k] : ctxs[k - 256];
        acc = fmaf(whr[q2], v, acc);
      }
#pragma unroll
      for (int off = 32; off > 0; off >>= 1) acc += __shfl_xor(acc, off);
      if (lane == 0) outg[(size_t)(b * TT + t) * 3 + o] = acc + bh;
    }
    // no barrier: next phase writes only zpart (disjoint from hbuf/ctxs)
  }
}

// ---------------- launch ----------------

extern "C" void kernel_launch(void* const* d_in, const int* in_sizes, int n_in,
                              void* d_out, int out_size, void* d_ws, size_t ws_size,
                              hipStream_t stream) {
  const float* x   = (const float*)d_in[0];
  const float* y   = (const float*)d_in[1];
  const float* a1w = (const float*)d_in[2];
  const float* a1b = (const float*)d_in[3];
  const float* a2w = (const float*)d_in[4];
  const float* a2b = (const float*)d_in[5];
  const float* a3w = (const float*)d_in[6];
  // d_in[7] = attn3_b: softmax-invariant constant, skipped
  const float* tw  = (const float*)d_in[8];
  const float* tb  = (const float*)d_in[9];
  const float* wih = (const float*)d_in[10];
  const float* whh = (const float*)d_in[11];
  const float* bih = (const float*)d_in[12];
  const float* bhh = (const float*)d_in[13];
  const float* f1w = (const float*)d_in[14];
  const float* f1b = (const float*)d_in[15];
  const float* f2w = (const float*)d_in[16];
  const float* f2b = (const float*)d_in[17];
  float* out = (float*)d_out;

  float* ws = (float*)d_ws;
  _Float16* z2h  = (_Float16*)ws;                       // 8,388,608 h = 4,194,304 f
  _Float16* xT   = (_Float16*)(ws + 4194304);           // 8,388,608 h
  float* a2wT    = ws + 8388608;                        // 65,536 f
  _Float16* a1p8 = (_Float16*)(ws + 8388608 + 65536);   // 131,072 h
  _Float16* whh8 = (_Float16*)(ws + 8388608 + 131072);  // 262,144 h
  _Float16* wc8  = (_Float16*)(ws + 8388608 + 262144);  // 270,336 h
  float* bcomb   = ws + 8388608 + 262144 + 135168;      // 1,024
  float* whead   = bcomb + 1024;                        // 1,536
  float* bhead   = whead + 1536;                        // 3

  k_transpose<<<dim3((256 * 256 + 255) / 256), dim3(256), 0, stream>>>(a2w, a2wT, 256, 256);
  k_z2x<<<dim3(2048), dim3(256), 0, stream>>>(x, a2wT, a2b, a1b, z2h, xT);
  k_pack_a1<<<dim3(512), dim3(256), 0, stream>>>(a1w, a1p8);
  k_pack_whh<<<dim3(1024), dim3(256), 0, stream>>>(whh, whh8);
  k_wcomb<<<dim3(1024), dim3(320), 0, stream>>>(wih, tw, tb, bih, bhh, wc8, bcomb);
  k_whead<<<dim3(1), dim3(512), 0, stream>>>(f1w, f1b, f2w, f2b, whead, bhead);

  k_decoder<<<dim3(256), dim3(1024), 0, stream>>>(z2h, xT, y, a3w, a1p8, whh8, wc8,
                                                  bcomb, whead, bhead, out);
}